// Round 1
// baseline (3581.670 us; speedup 1.0000x reference)
//
#include <hip/hip_runtime.h>
#include <hip/hip_bf16.h>

// GCN: 3x GCNConv (sym-norm, self-loops) + linear head.
// N=50000 nodes, E=800000 edges, F: 128 -> 128 -> 128 -> 64 -> 1.
// Round 0 strategy: fp32 everywhere. GEMM with full-W LDS staging.
// Aggregation: edge-parallel gather + fp32 global atomics into acc.

#define N_NODES 50000
#define N_EDGES 800000

__global__ __launch_bounds__(256) void init_deg_kernel(float* deg, int n) {
    int i = blockIdx.x * 256 + threadIdx.x;
    if (i < n) deg[i] = 1.0f;  // self-loop contributes 1
}

__global__ __launch_bounds__(256) void deg_edge_kernel(const int* __restrict__ dst,
                                                       float* __restrict__ deg, int nE) {
    int i = blockIdx.x * 256 + threadIdx.x;
    if (i < nE) atomicAdd(&deg[dst[i]], 1.0f);
}

__global__ __launch_bounds__(256) void dis_kernel(const float* __restrict__ deg,
                                                  float* __restrict__ dis, int n) {
    int i = blockIdx.x * 256 + threadIdx.x;
    if (i < n) dis[i] = rsqrtf(deg[i]);  // deg >= 1 always (self-loop)
}

// C[M x NOUT] = A[M x 128] @ W[128 x NOUT]; W fully staged in LDS.
// Block tile: 32 rows x NOUT cols, 256 threads.
template <int NOUT>
__global__ __launch_bounds__(256) void gemm_kernel(const float* __restrict__ A,
                                                   const float* __restrict__ W,
                                                   float* __restrict__ C, int M) {
    constexpr int CG = NOUT / 4;    // column groups (float4 each): 32 or 16
    constexpr int RG = 256 / CG;    // row groups: 8 or 16
    constexpr int RPT = 32 / RG;    // rows per thread: 4 or 2

    __shared__ float sW[128 * NOUT];
    __shared__ float sA[32 * 128];

    int tid = threadIdx.x;
    int cg = tid % CG;
    int rg = tid / CG;
    int row0 = blockIdx.x * 32;

    // stage W (128*NOUT floats)
    for (int i = tid; i < 128 * NOUT / 4; i += 256)
        ((float4*)sW)[i] = ((const float4*)W)[i];
    // stage A tile (32 rows x 128)
    for (int i = tid; i < 32 * 128 / 4; i += 256) {
        int r = i >> 5;          // 32 float4 per row
        int c = i & 31;
        int gr = row0 + r;
        float4 v = make_float4(0.f, 0.f, 0.f, 0.f);
        if (gr < M) v = ((const float4*)(A + (size_t)gr * 128))[c];
        ((float4*)sA)[i] = v;
    }
    __syncthreads();

    float acc[RPT][4] = {};
#pragma unroll 8
    for (int k = 0; k < 128; ++k) {
        float4 w = ((float4*)sW)[k * CG + cg];
#pragma unroll
        for (int r = 0; r < RPT; ++r) {
            float a = sA[(rg * RPT + r) * 128 + k];
            acc[r][0] += a * w.x;
            acc[r][1] += a * w.y;
            acc[r][2] += a * w.z;
            acc[r][3] += a * w.w;
        }
    }
    for (int r = 0; r < RPT; ++r) {
        int gr = row0 + rg * RPT + r;
        if (gr < M)
            ((float4*)(C + (size_t)gr * NOUT))[cg] =
                make_float4(acc[r][0], acc[r][1], acc[r][2], acc[r][3]);
    }
}

// Edge-parallel scatter: acc[dst] += t[src] * dis[src]*dis[dst]
template <int F>
__global__ __launch_bounds__(256) void scatter_kernel(const int* __restrict__ srcv,
                                                      const int* __restrict__ dstv,
                                                      const float* __restrict__ dis,
                                                      const float* __restrict__ t,
                                                      float* __restrict__ acc, int nE) {
    constexpr int TPE = F / 4;  // threads per edge
    int tid = blockIdx.x * 256 + threadIdx.x;
    int e = tid / TPE;
    if (e >= nE) return;
    int f = (tid % TPE) * 4;
    int s = srcv[e];
    int d = dstv[e];
    float norm = dis[s] * dis[d];
    float4 v = *((const float4*)(t + (size_t)s * F + f));
    float* o = acc + (size_t)d * F + f;
    atomicAdd(o + 0, v.x * norm);
    atomicAdd(o + 1, v.y * norm);
    atomicAdd(o + 2, v.z * norm);
    atomicAdd(o + 3, v.w * norm);
}

// h[i] = maybe_relu(acc[i] + t[i]*dis[i]^2 + bias)
template <int F, bool RELU>
__global__ __launch_bounds__(256) void finish_kernel(const float* __restrict__ t,
                                                     const float* __restrict__ dis,
                                                     const float* __restrict__ bias,
                                                     const float* __restrict__ acc,
                                                     float* __restrict__ hout, int n) {
    constexpr int FG = F / 4;
    int idx = blockIdx.x * 256 + threadIdx.x;
    if (idx >= n * FG) return;
    int node = idx / FG;
    int f4 = idx % FG;
    float dd = dis[node];
    float selfn = dd * dd;
    float4 a = ((const float4*)acc)[idx];
    float4 tv = ((const float4*)t)[idx];
    float4 b = ((const float4*)bias)[f4];
    float4 r;
    r.x = a.x + tv.x * selfn + b.x;
    r.y = a.y + tv.y * selfn + b.y;
    r.z = a.z + tv.z * selfn + b.z;
    r.w = a.w + tv.w * selfn + b.w;
    if (RELU) {
        r.x = fmaxf(r.x, 0.f);
        r.y = fmaxf(r.y, 0.f);
        r.z = fmaxf(r.z, 0.f);
        r.w = fmaxf(r.w, 0.f);
    }
    ((float4*)hout)[idx] = r;
}

// out[n] = dot(h3[n, 0:64], Wout) + bout ; one wave per node
__global__ __launch_bounds__(256) void outdot_kernel(const float* __restrict__ h3,
                                                     const float* __restrict__ Wout,
                                                     const float* __restrict__ bout,
                                                     float* __restrict__ out, int n) {
    int wave = (blockIdx.x * 256 + threadIdx.x) >> 6;
    int lane = threadIdx.x & 63;
    if (wave >= n) return;
    float v = h3[(size_t)wave * 64 + lane] * Wout[lane];
#pragma unroll
    for (int off = 32; off > 0; off >>= 1) v += __shfl_down(v, off);
    if (lane == 0) out[wave] = v + bout[0];
}

extern "C" void kernel_launch(void* const* d_in, const int* in_sizes, int n_in,
                              void* d_out, int out_size, void* d_ws, size_t ws_size,
                              hipStream_t stream) {
    const float* x    = (const float*)d_in[0];
    const int*   ei   = (const int*)d_in[1];  // [2, E] flat: src then dst
    const float* W1   = (const float*)d_in[2];
    const float* b1   = (const float*)d_in[3];
    const float* Wh   = (const float*)d_in[4];
    const float* bh   = (const float*)d_in[5];
    const float* W2   = (const float*)d_in[6];
    const float* b2   = (const float*)d_in[7];
    const float* Wout = (const float*)d_in[8];
    const float* bout = (const float*)d_in[9];

    const int N = N_NODES;
    const int E = N_EDGES;
    const int* srcv = ei;
    const int* dstv = ei + E;

    float* out  = (float*)d_out;            // [N]
    float* hout = (float*)d_out + N;        // [N x 64]

    float* ws   = (float*)d_ws;
    float* deg  = ws;                       // N
    float* dis  = ws + N;                   // N
    float* bufA = ws + 2 * N;               // N*128 (t)
    float* bufB = bufA + (size_t)N * 128;   // N*128 (acc / h)

    // --- normalization ---
    init_deg_kernel<<<(N + 255) / 256, 256, 0, stream>>>(deg, N);
    deg_edge_kernel<<<(E + 255) / 256, 256, 0, stream>>>(dstv, deg, E);
    dis_kernel<<<(N + 255) / 256, 256, 0, stream>>>(deg, dis, N);

    // --- layer 1: h1 = relu(agg(x@W1) + b1) ---
    gemm_kernel<128><<<(N + 31) / 32, 256, 0, stream>>>(x, W1, bufA, N);
    hipMemsetAsync(bufB, 0, (size_t)N * 128 * sizeof(float), stream);
    scatter_kernel<128><<<((size_t)E * 32 + 255) / 256, 256, 0, stream>>>(
        srcv, dstv, dis, bufA, bufB, E);
    finish_kernel<128, true><<<((size_t)N * 32 + 255) / 256, 256, 0, stream>>>(
        bufA, dis, b1, bufB, bufB, N);

    // --- layer 2: h2 = relu(agg(h1@Wh) + bh) ---
    gemm_kernel<128><<<(N + 31) / 32, 256, 0, stream>>>(bufB, Wh, bufA, N);
    hipMemsetAsync(bufB, 0, (size_t)N * 128 * sizeof(float), stream);
    scatter_kernel<128><<<((size_t)E * 32 + 255) / 256, 256, 0, stream>>>(
        srcv, dstv, dis, bufA, bufB, E);
    finish_kernel<128, true><<<((size_t)N * 32 + 255) / 256, 256, 0, stream>>>(
        bufA, dis, bh, bufB, bufB, N);

    // --- layer 3: h3 = agg(h2@W2) + b2  (no relu), straight into d_out ---
    gemm_kernel<64><<<(N + 31) / 32, 256, 0, stream>>>(bufB, W2, bufA, N);
    hipMemsetAsync(hout, 0, (size_t)N * 64 * sizeof(float), stream);
    scatter_kernel<64><<<((size_t)E * 16 + 255) / 256, 256, 0, stream>>>(
        srcv, dstv, dis, bufA, hout, E);
    finish_kernel<64, false><<<((size_t)N * 16 + 255) / 256, 256, 0, stream>>>(
        bufA, dis, b2, hout, hout, N);

    // --- head: out = h3 @ Wout + bout ---
    outdot_kernel<<<((size_t)N * 64 + 255) / 256, 256, 0, stream>>>(hout, Wout, bout, out, N);
}

// Round 2
// 614.118 us; speedup vs baseline: 5.8322x; 5.8322x over previous
//
#include <hip/hip_runtime.h>
#include <hip/hip_bf16.h>

// GCN: 3x GCNConv (sym-norm, self-loops) + linear head.
// N=50000 nodes, E=800000 edges, F: 128 -> 128 -> 128 -> 64 -> 1.
// Round 2: gather-based aggregation over device-built CSR (counting sort by
// dst). Kills the 102M fp32 global atomics that were 92% of round-1 runtime
// (WRITE_SIZE 1.6 GB/dispatch -> ~26 MB). Self-loop+bias+relu fused into the
// aggregate; scalar head fused into the F=64 aggregate.

#define N_NODES 50000
#define N_EDGES 800000

// ---------- CSR build ----------

__global__ __launch_bounds__(256) void count_kernel(const int* __restrict__ dst,
                                                    int* __restrict__ cnt, int nE) {
    int i = blockIdx.x * 256 + threadIdx.x;
    if (i < nE) atomicAdd(&cnt[dst[i]], 1);
}

__global__ __launch_bounds__(256) void dis_kernel(const int* __restrict__ cnt,
                                                  float* __restrict__ dis, int n) {
    int i = blockIdx.x * 256 + threadIdx.x;
    if (i < n) dis[i] = rsqrtf((float)(cnt[i] + 1));  // +1 self-loop, always >=1
}

// Single-block exclusive scan (Hillis-Steele per 1024-chunk + running carry).
__global__ __launch_bounds__(1024) void scan_kernel(const int* __restrict__ cnt,
                                                    int* __restrict__ rowoff, int n) {
    __shared__ int s[1024];
    __shared__ int carry_s;
    int tid = threadIdx.x;
    if (tid == 0) carry_s = 0;
    for (int base = 0; base < n; base += 1024) {
        int i = base + tid;
        int v = (i < n) ? cnt[i] : 0;
        __syncthreads();          // protect s + carry_s from prev iteration
        s[tid] = v;
        __syncthreads();
        for (int off = 1; off < 1024; off <<= 1) {
            int t = (tid >= off) ? s[tid - off] : 0;
            __syncthreads();
            s[tid] += t;
            __syncthreads();
        }
        int carry = carry_s;
        if (i < n) rowoff[i] = carry + s[tid] - v;  // exclusive
        __syncthreads();
        if (tid == 0) carry_s = carry + s[1023];
    }
    __syncthreads();
    if (tid == 0) rowoff[n] = carry_s;  // == E
}

__global__ __launch_bounds__(256) void copy_int_kernel(const int* __restrict__ a,
                                                       int* __restrict__ b, int n) {
    int i = blockIdx.x * 256 + threadIdx.x;
    if (i < n) b[i] = a[i];
}

__global__ __launch_bounds__(256) void fill_kernel(const int* __restrict__ srcv,
                                                   const int* __restrict__ dstv,
                                                   int* __restrict__ cursor,
                                                   int* __restrict__ csr_src, int nE) {
    int i = blockIdx.x * 256 + threadIdx.x;
    if (i < nE) {
        int d = dstv[i];
        int pos = atomicAdd(&cursor[d], 1);
        csr_src[pos] = srcv[i];
    }
}

// ---------- GEMM: C[M x NOUT] = A[M x 128] @ W[128 x NOUT], W in LDS ----------
template <int NOUT>
__global__ __launch_bounds__(256) void gemm_kernel(const float* __restrict__ A,
                                                   const float* __restrict__ W,
                                                   float* __restrict__ C, int M) {
    constexpr int CG = NOUT / 4;    // float4 column groups
    constexpr int RG = 256 / CG;
    constexpr int RPT = 32 / RG;

    __shared__ float sW[128 * NOUT];
    __shared__ float sA[32 * 128];

    int tid = threadIdx.x;
    int cg = tid % CG;
    int rg = tid / CG;
    int row0 = blockIdx.x * 32;

    for (int i = tid; i < 128 * NOUT / 4; i += 256)
        ((float4*)sW)[i] = ((const float4*)W)[i];
    for (int i = tid; i < 32 * 128 / 4; i += 256) {
        int r = i >> 5;
        int c = i & 31;
        int gr = row0 + r;
        float4 v = make_float4(0.f, 0.f, 0.f, 0.f);
        if (gr < M) v = ((const float4*)(A + (size_t)gr * 128))[c];
        ((float4*)sA)[i] = v;
    }
    __syncthreads();

    float acc[RPT][4] = {};
#pragma unroll 8
    for (int k = 0; k < 128; ++k) {
        float4 w = ((float4*)sW)[k * CG + cg];
#pragma unroll
        for (int r = 0; r < RPT; ++r) {
            float a = sA[(rg * RPT + r) * 128 + k];
            acc[r][0] += a * w.x;
            acc[r][1] += a * w.y;
            acc[r][2] += a * w.z;
            acc[r][3] += a * w.w;
        }
    }
    for (int r = 0; r < RPT; ++r) {
        int gr = row0 + rg * RPT + r;
        if (gr < M)
            ((float4*)(C + (size_t)gr * NOUT))[cg] =
                make_float4(acc[r][0], acc[r][1], acc[r][2], acc[r][3]);
    }
}

// ---------- Gather aggregation: one wave per node ----------
// h[n] = relu?(sum_{s in N(n)} t[s]*dis[s]*dis[n] + t[n]*dis[n]^2 + bias)
// F=128: 2 floats/lane. Fused epilogue writes hout.
__global__ __launch_bounds__(256) void aggregate128_kernel(
    const int* __restrict__ rowoff, const int* __restrict__ csr_src,
    const float* __restrict__ dis, const float* __restrict__ t,
    const float* __restrict__ bias, float* __restrict__ hout, int n) {
    int node = (blockIdx.x * 256 + threadIdx.x) >> 6;
    int lane = threadIdx.x & 63;
    if (node >= n) return;
    float dd = dis[node];
    const float2* trow;
    trow = (const float2*)(t + (size_t)node * 128) + lane;
    float2 self = *trow;
    float2 b = ((const float2*)bias)[lane];
    float selfn = dd * dd;
    float ax = self.x * selfn + b.x;
    float ay = self.y * selfn + b.y;
    int beg = rowoff[node], end = rowoff[node + 1];
    for (int i = beg; i < end; ++i) {
        int s = csr_src[i];
        float w = dis[s] * dd;
        float2 v = *((const float2*)(t + (size_t)s * 128) + lane);
        ax += v.x * w;
        ay += v.y * w;
    }
    ax = fmaxf(ax, 0.f);
    ay = fmaxf(ay, 0.f);
    *((float2*)(hout + (size_t)node * 128) + lane) = make_float2(ax, ay);
}

// F=64, no relu, fused head: out[n] = dot(h3[n], Wout) + bout
__global__ __launch_bounds__(256) void aggregate64_head_kernel(
    const int* __restrict__ rowoff, const int* __restrict__ csr_src,
    const float* __restrict__ dis, const float* __restrict__ t,
    const float* __restrict__ bias, const float* __restrict__ Wout,
    const float* __restrict__ bout, float* __restrict__ hout,
    float* __restrict__ out, int n) {
    int node = (blockIdx.x * 256 + threadIdx.x) >> 6;
    int lane = threadIdx.x & 63;
    if (node >= n) return;
    float dd = dis[node];
    float acc = t[(size_t)node * 64 + lane] * dd * dd + bias[lane];
    int beg = rowoff[node], end = rowoff[node + 1];
    for (int i = beg; i < end; ++i) {
        int s = csr_src[i];
        acc += t[(size_t)s * 64 + lane] * (dis[s] * dd);
    }
    hout[(size_t)node * 64 + lane] = acc;
    float p = acc * Wout[lane];
#pragma unroll
    for (int off = 32; off > 0; off >>= 1) p += __shfl_down(p, off);
    if (lane == 0) out[node] = p + bout[0];
}

extern "C" void kernel_launch(void* const* d_in, const int* in_sizes, int n_in,
                              void* d_out, int out_size, void* d_ws, size_t ws_size,
                              hipStream_t stream) {
    const float* x    = (const float*)d_in[0];
    const int*   ei   = (const int*)d_in[1];  // [2, E] flat: src then dst
    const float* W1   = (const float*)d_in[2];
    const float* b1   = (const float*)d_in[3];
    const float* Wh   = (const float*)d_in[4];
    const float* bh   = (const float*)d_in[5];
    const float* W2   = (const float*)d_in[6];
    const float* b2   = (const float*)d_in[7];
    const float* Wout = (const float*)d_in[8];
    const float* bout = (const float*)d_in[9];

    const int N = N_NODES;
    const int E = N_EDGES;
    const int* srcv = ei;
    const int* dstv = ei + E;

    float* out  = (float*)d_out;            // [N]
    float* hout = (float*)d_out + N;        // [N x 64]

    char* ws = (char*)d_ws;
    int*   cnt     = (int*)ws;                          ws += sizeof(int) * N;
    int*   rowoff  = (int*)ws;                          ws += sizeof(int) * (N + 1);
    int*   cursor  = (int*)ws;                          ws += sizeof(int) * N;
    int*   csr_src = (int*)ws;                          ws += sizeof(int) * E;
    float* dis     = (float*)ws;                        ws += sizeof(float) * N;
    float* bufA    = (float*)ws;                        ws += sizeof(float) * (size_t)N * 128;
    float* bufB    = (float*)ws;

    // --- CSR build + normalization ---
    hipMemsetAsync(cnt, 0, sizeof(int) * N, stream);
    count_kernel<<<(E + 255) / 256, 256, 0, stream>>>(dstv, cnt, E);
    dis_kernel<<<(N + 255) / 256, 256, 0, stream>>>(cnt, dis, N);
    scan_kernel<<<1, 1024, 0, stream>>>(cnt, rowoff, N);
    copy_int_kernel<<<(N + 255) / 256, 256, 0, stream>>>(rowoff, cursor, N);
    fill_kernel<<<(E + 255) / 256, 256, 0, stream>>>(srcv, dstv, cursor, csr_src, E);

    // --- layer 1: h1 = relu(agg(x@W1) + b1) ---
    gemm_kernel<128><<<(N + 31) / 32, 256, 0, stream>>>(x, W1, bufA, N);
    aggregate128_kernel<<<((size_t)N * 64 + 255) / 256, 256, 0, stream>>>(
        rowoff, csr_src, dis, bufA, b1, bufB, N);

    // --- layer 2: h2 = relu(agg(h1@Wh) + bh) ---
    gemm_kernel<128><<<(N + 31) / 32, 256, 0, stream>>>(bufB, Wh, bufA, N);
    aggregate128_kernel<<<((size_t)N * 64 + 255) / 256, 256, 0, stream>>>(
        rowoff, csr_src, dis, bufA, bh, bufB, N);

    // --- layer 3 + head: h3 = agg(h2@W2) + b2 ; out = h3@Wout + bout ---
    gemm_kernel<64><<<(N + 31) / 32, 256, 0, stream>>>(bufB, W2, bufA, N);
    aggregate64_head_kernel<<<((size_t)N * 64 + 255) / 256, 256, 0, stream>>>(
        rowoff, csr_src, dis, bufA, b2, Wout, bout, hout, out, N);
}

// Round 3
// 454.843 us; speedup vs baseline: 7.8745x; 1.3502x over previous
//
#include <hip/hip_runtime.h>
#include <hip/hip_bf16.h>

// GCN: 3x GCNConv (sym-norm, self-loops) + linear head.
// N=50000 nodes, E=800000 edges, F: 128 -> 128 -> 128 -> 64 -> 1.
// Round 3: latency-bound gather fix.
//  - GEMM epilogue pre-scales rows by dis[row]  -> inner gather loop is
//    index+row+add only (no dis[s] fetch, shorter dep chain).
//  - Neighbor loop unrolled x4 (4 row-gathers in flight per wave).
//  - 3-phase scan replaces single-block scan; dis/cursor fused into apply.

#define N_NODES 50000
#define N_EDGES 800000

// ---------- CSR build ----------

__global__ __launch_bounds__(256) void count_kernel(const int* __restrict__ dst,
                                                    int* __restrict__ cnt, int nE) {
    int i = blockIdx.x * 256 + threadIdx.x;
    if (i < nE) atomicAdd(&cnt[dst[i]], 1);
}

// phase 1: per-block (256-chunk) sums
__global__ __launch_bounds__(256) void scan_bsum_kernel(const int* __restrict__ cnt,
                                                        int* __restrict__ bsum, int n) {
    int i = blockIdx.x * 256 + threadIdx.x;
    int v = (i < n) ? cnt[i] : 0;
#pragma unroll
    for (int off = 32; off > 0; off >>= 1) v += __shfl_down(v, off);
    __shared__ int wsum[4];
    int lane = threadIdx.x & 63, w = threadIdx.x >> 6;
    if (lane == 0) wsum[w] = v;
    __syncthreads();
    if (threadIdx.x == 0) bsum[blockIdx.x] = wsum[0] + wsum[1] + wsum[2] + wsum[3];
}

// phase 2: single-block exclusive scan of nb (<=256) block sums
__global__ __launch_bounds__(256) void scan_boff_kernel(const int* __restrict__ bsum,
                                                        int* __restrict__ boff,
                                                        int* __restrict__ rowoff_last,
                                                        int nb) {
    __shared__ int s[256];
    int tid = threadIdx.x;
    int v = (tid < nb) ? bsum[tid] : 0;
    s[tid] = v;
    __syncthreads();
    for (int off = 1; off < 256; off <<= 1) {
        int t = (tid >= off) ? s[tid - off] : 0;
        __syncthreads();
        s[tid] += t;
        __syncthreads();
    }
    if (tid < nb) boff[tid] = s[tid] - v;           // exclusive
    if (tid == 255) *rowoff_last = s[255];          // total == E
}

// phase 3: per-block exclusive scan + block offset; fused dis + cursor writes
__global__ __launch_bounds__(256) void scan_apply_kernel(const int* __restrict__ cnt,
                                                         const int* __restrict__ boff,
                                                         int* __restrict__ rowoff,
                                                         int* __restrict__ cursor,
                                                         float* __restrict__ dis, int n) {
    __shared__ int s[256];
    int tid = threadIdx.x;
    int i = blockIdx.x * 256 + tid;
    int v = (i < n) ? cnt[i] : 0;
    s[tid] = v;
    __syncthreads();
    for (int off = 1; off < 256; off <<= 1) {
        int t = (tid >= off) ? s[tid - off] : 0;
        __syncthreads();
        s[tid] += t;
        __syncthreads();
    }
    if (i < n) {
        int ex = boff[blockIdx.x] + s[tid] - v;
        rowoff[i] = ex;
        cursor[i] = ex;
        dis[i] = rsqrtf((float)(v + 1));  // +1 self-loop
    }
}

__global__ __launch_bounds__(256) void fill_kernel(const int* __restrict__ srcv,
                                                   const int* __restrict__ dstv,
                                                   int* __restrict__ cursor,
                                                   int* __restrict__ csr_src, int nE) {
    int i = blockIdx.x * 256 + threadIdx.x;
    if (i < nE) {
        int d = dstv[i];
        int pos = atomicAdd(&cursor[d], 1);
        csr_src[pos] = srcv[i];
    }
}

// ---------- GEMM: C[r] = (A[r] @ W) * scale[r], W in LDS ----------
template <int NOUT>
__global__ __launch_bounds__(256) void gemm_kernel(const float* __restrict__ A,
                                                   const float* __restrict__ W,
                                                   const float* __restrict__ scale,
                                                   float* __restrict__ C, int M) {
    constexpr int CG = NOUT / 4;    // float4 column groups
    constexpr int RG = 256 / CG;
    constexpr int RPT = 32 / RG;

    __shared__ float sW[128 * NOUT];
    __shared__ float sA[32 * 128];

    int tid = threadIdx.x;
    int cg = tid % CG;
    int rg = tid / CG;
    int row0 = blockIdx.x * 32;

    for (int i = tid; i < 128 * NOUT / 4; i += 256)
        ((float4*)sW)[i] = ((const float4*)W)[i];
    for (int i = tid; i < 32 * 128 / 4; i += 256) {
        int r = i >> 5;
        int c = i & 31;
        int gr = row0 + r;
        float4 v = make_float4(0.f, 0.f, 0.f, 0.f);
        if (gr < M) v = ((const float4*)(A + (size_t)gr * 128))[c];
        ((float4*)sA)[i] = v;
    }
    __syncthreads();

    float acc[RPT][4] = {};
#pragma unroll 8
    for (int k = 0; k < 128; ++k) {
        float4 w = ((float4*)sW)[k * CG + cg];
#pragma unroll
        for (int r = 0; r < RPT; ++r) {
            float a = sA[(rg * RPT + r) * 128 + k];
            acc[r][0] += a * w.x;
            acc[r][1] += a * w.y;
            acc[r][2] += a * w.z;
            acc[r][3] += a * w.w;
        }
    }
    for (int r = 0; r < RPT; ++r) {
        int gr = row0 + rg * RPT + r;
        if (gr < M) {
            float sc = scale[gr];
            ((float4*)(C + (size_t)gr * NOUT))[cg] =
                make_float4(acc[r][0] * sc, acc[r][1] * sc, acc[r][2] * sc, acc[r][3] * sc);
        }
    }
}

// ---------- Gather aggregation (pre-scaled rows): one wave per node ----------
// h[n] = relu(dd*(tp[n] + sum tp[s]) + bias), tp = (A@W)*dis row-scaled
__global__ __launch_bounds__(256) void aggregate128_kernel(
    const int* __restrict__ rowoff, const int* __restrict__ csr_src,
    const float* __restrict__ dis, const float* __restrict__ tp,
    const float* __restrict__ bias, float* __restrict__ hout, int n) {
    int node = (blockIdx.x * 256 + threadIdx.x) >> 6;
    int lane = threadIdx.x & 63;
    if (node >= n) return;
    float dd = dis[node];
    const float2* base = (const float2*)tp + lane;  // row stride = 64 float2
    float2 self = base[(size_t)node * 64];
    float ax = self.x, ay = self.y;
    int beg = rowoff[node], end = rowoff[node + 1];
    int i = beg;
    for (; i + 4 <= end; i += 4) {
        int s0 = csr_src[i], s1 = csr_src[i + 1], s2 = csr_src[i + 2], s3 = csr_src[i + 3];
        float2 v0 = base[(size_t)s0 * 64];
        float2 v1 = base[(size_t)s1 * 64];
        float2 v2 = base[(size_t)s2 * 64];
        float2 v3 = base[(size_t)s3 * 64];
        ax += (v0.x + v1.x) + (v2.x + v3.x);
        ay += (v0.y + v1.y) + (v2.y + v3.y);
    }
    for (; i < end; ++i) {
        float2 v = base[(size_t)csr_src[i] * 64];
        ax += v.x;
        ay += v.y;
    }
    float2 b = ((const float2*)bias)[lane];
    ax = fmaxf(ax * dd + b.x, 0.f);
    ay = fmaxf(ay * dd + b.y, 0.f);
    ((float2*)hout)[(size_t)node * 64 + lane] = make_float2(ax, ay);
}

// F=64, no relu, fused head: h3 = dd*(tp[n]+sum tp[s]) + b2 ; out = h3@Wout + bout
__global__ __launch_bounds__(256) void aggregate64_head_kernel(
    const int* __restrict__ rowoff, const int* __restrict__ csr_src,
    const float* __restrict__ dis, const float* __restrict__ tp,
    const float* __restrict__ bias, const float* __restrict__ Wout,
    const float* __restrict__ bout, float* __restrict__ hout,
    float* __restrict__ out, int n) {
    int node = (blockIdx.x * 256 + threadIdx.x) >> 6;
    int lane = threadIdx.x & 63;
    if (node >= n) return;
    float dd = dis[node];
    const float* base = tp + lane;
    float acc = base[(size_t)node * 64];
    int beg = rowoff[node], end = rowoff[node + 1];
    int i = beg;
    for (; i + 4 <= end; i += 4) {
        int s0 = csr_src[i], s1 = csr_src[i + 1], s2 = csr_src[i + 2], s3 = csr_src[i + 3];
        float v0 = base[(size_t)s0 * 64];
        float v1 = base[(size_t)s1 * 64];
        float v2 = base[(size_t)s2 * 64];
        float v3 = base[(size_t)s3 * 64];
        acc += (v0 + v1) + (v2 + v3);
    }
    for (; i < end; ++i) acc += base[(size_t)csr_src[i] * 64];
    acc = acc * dd + bias[lane];
    hout[(size_t)node * 64 + lane] = acc;
    float p = acc * Wout[lane];
#pragma unroll
    for (int off = 32; off > 0; off >>= 1) p += __shfl_down(p, off);
    if (lane == 0) out[node] = p + bout[0];
}

extern "C" void kernel_launch(void* const* d_in, const int* in_sizes, int n_in,
                              void* d_out, int out_size, void* d_ws, size_t ws_size,
                              hipStream_t stream) {
    const float* x    = (const float*)d_in[0];
    const int*   ei   = (const int*)d_in[1];  // [2, E] flat: src then dst
    const float* W1   = (const float*)d_in[2];
    const float* b1   = (const float*)d_in[3];
    const float* Wh   = (const float*)d_in[4];
    const float* bh   = (const float*)d_in[5];
    const float* W2   = (const float*)d_in[6];
    const float* b2   = (const float*)d_in[7];
    const float* Wout = (const float*)d_in[8];
    const float* bout = (const float*)d_in[9];

    const int N = N_NODES;
    const int E = N_EDGES;
    const int NB = (N + 255) / 256;  // 196 blocks, <=256 for single-block phase 2
    const int* srcv = ei;
    const int* dstv = ei + E;

    float* out  = (float*)d_out;            // [N]
    float* hout = (float*)d_out + N;        // [N x 64]

    char* ws = (char*)d_ws;
    int*   cnt     = (int*)ws;                          ws += sizeof(int) * N;
    int*   rowoff  = (int*)ws;                          ws += sizeof(int) * (N + 1);
    int*   cursor  = (int*)ws;                          ws += sizeof(int) * N;
    int*   bsum    = (int*)ws;                          ws += sizeof(int) * 256;
    int*   boff    = (int*)ws;                          ws += sizeof(int) * 256;
    int*   csr_src = (int*)ws;                          ws += sizeof(int) * E;
    float* dis     = (float*)ws;                        ws += sizeof(float) * N;
    float* bufA    = (float*)ws;                        ws += sizeof(float) * (size_t)N * 128;
    float* bufB    = (float*)ws;

    // --- CSR build + normalization ---
    hipMemsetAsync(cnt, 0, sizeof(int) * N, stream);
    count_kernel<<<(E + 255) / 256, 256, 0, stream>>>(dstv, cnt, E);
    scan_bsum_kernel<<<NB, 256, 0, stream>>>(cnt, bsum, N);
    scan_boff_kernel<<<1, 256, 0, stream>>>(bsum, boff, rowoff + N, NB);
    scan_apply_kernel<<<NB, 256, 0, stream>>>(cnt, boff, rowoff, cursor, dis, N);
    fill_kernel<<<(E + 255) / 256, 256, 0, stream>>>(srcv, dstv, cursor, csr_src, E);

    // --- layer 1: h1 = relu(agg(x@W1) + b1) ---
    gemm_kernel<128><<<(N + 31) / 32, 256, 0, stream>>>(x, W1, dis, bufA, N);
    aggregate128_kernel<<<((size_t)N * 64 + 255) / 256, 256, 0, stream>>>(
        rowoff, csr_src, dis, bufA, b1, bufB, N);

    // --- layer 2: h2 = relu(agg(h1@Wh) + bh) ---
    gemm_kernel<128><<<(N + 31) / 32, 256, 0, stream>>>(bufB, Wh, dis, bufA, N);
    aggregate128_kernel<<<((size_t)N * 64 + 255) / 256, 256, 0, stream>>>(
        rowoff, csr_src, dis, bufA, bh, bufB, N);

    // --- layer 3 + head: h3 = agg(h2@W2) + b2 ; out = h3@Wout + bout ---
    gemm_kernel<64><<<(N + 31) / 32, 256, 0, stream>>>(bufB, W2, dis, bufA, N);
    aggregate64_head_kernel<<<((size_t)N * 64 + 255) / 256, 256, 0, stream>>>(
        rowoff, csr_src, dis, bufA, b2, Wout, bout, hout, out, N);
}

// Round 4
// 402.837 us; speedup vs baseline: 8.8911x; 1.1291x over previous
//
#include <hip/hip_runtime.h>
#include <hip/hip_bf16.h>

// GCN: 3x GCNConv (sym-norm, self-loops) + linear head.
// N=50000 nodes, E=800000 edges, F: 128 -> 128 -> 128 -> 64 -> 1.
// Round 4: aggregate fetch is at the fp32 structural floor (8 XCDs x 25.6 MB
// = 205 MB compulsory; measured 225 MB). Shrink the gathered matrix:
//  - GEMM writes t' = (A@W)*dis[row] as BF16 (rows 256 B / 128 B).
//  - Aggregate gathers bf16, accumulates fp32 (bf16->f32 is exact shl 16).
//  - GEMM inner loop restructured to float4 sA reads (was LDS-bound:
//    4x ds_read_b32 per k; now b128 per 4k -> VALU-bound).
// h outputs and GEMM inputs stay fp32 (precision preserved in the dense path).

#define N_NODES 50000
#define N_EDGES 800000

static __device__ __forceinline__ unsigned short f2bf(float f) {
    __hip_bfloat16 h = __float2bfloat16(f);  // RNE
    return *reinterpret_cast<unsigned short*>(&h);
}
static __device__ __forceinline__ float bf2f(unsigned short u) {
    return __uint_as_float(((unsigned)u) << 16);  // exact
}

// ---------- CSR build ----------

__global__ __launch_bounds__(256) void count_kernel(const int* __restrict__ dst,
                                                    int* __restrict__ cnt, int nE) {
    int i = blockIdx.x * 256 + threadIdx.x;
    if (i < nE) atomicAdd(&cnt[dst[i]], 1);
}

__global__ __launch_bounds__(256) void scan_bsum_kernel(const int* __restrict__ cnt,
                                                        int* __restrict__ bsum, int n) {
    int i = blockIdx.x * 256 + threadIdx.x;
    int v = (i < n) ? cnt[i] : 0;
#pragma unroll
    for (int off = 32; off > 0; off >>= 1) v += __shfl_down(v, off);
    __shared__ int wsum[4];
    int lane = threadIdx.x & 63, w = threadIdx.x >> 6;
    if (lane == 0) wsum[w] = v;
    __syncthreads();
    if (threadIdx.x == 0) bsum[blockIdx.x] = wsum[0] + wsum[1] + wsum[2] + wsum[3];
}

__global__ __launch_bounds__(256) void scan_boff_kernel(const int* __restrict__ bsum,
                                                        int* __restrict__ boff,
                                                        int* __restrict__ rowoff_last,
                                                        int nb) {
    __shared__ int s[256];
    int tid = threadIdx.x;
    int v = (tid < nb) ? bsum[tid] : 0;
    s[tid] = v;
    __syncthreads();
    for (int off = 1; off < 256; off <<= 1) {
        int t = (tid >= off) ? s[tid - off] : 0;
        __syncthreads();
        s[tid] += t;
        __syncthreads();
    }
    if (tid < nb) boff[tid] = s[tid] - v;           // exclusive
    if (tid == 255) *rowoff_last = s[255];          // total == E
}

__global__ __launch_bounds__(256) void scan_apply_kernel(const int* __restrict__ cnt,
                                                         const int* __restrict__ boff,
                                                         int* __restrict__ rowoff,
                                                         int* __restrict__ cursor,
                                                         float* __restrict__ dis, int n) {
    __shared__ int s[256];
    int tid = threadIdx.x;
    int i = blockIdx.x * 256 + tid;
    int v = (i < n) ? cnt[i] : 0;
    s[tid] = v;
    __syncthreads();
    for (int off = 1; off < 256; off <<= 1) {
        int t = (tid >= off) ? s[tid - off] : 0;
        __syncthreads();
        s[tid] += t;
        __syncthreads();
    }
    if (i < n) {
        int ex = boff[blockIdx.x] + s[tid] - v;
        rowoff[i] = ex;
        cursor[i] = ex;
        dis[i] = rsqrtf((float)(v + 1));  // +1 self-loop
    }
}

__global__ __launch_bounds__(256) void fill_kernel(const int* __restrict__ srcv,
                                                   const int* __restrict__ dstv,
                                                   int* __restrict__ cursor,
                                                   int* __restrict__ csr_src, int nE) {
    int i = blockIdx.x * 256 + threadIdx.x;
    if (i < nE) {
        int d = dstv[i];
        int pos = atomicAdd(&cursor[d], 1);
        csr_src[pos] = srcv[i];
    }
}

// ---------- GEMM: C[r] = bf16((A[r] @ W) * scale[r]), W in LDS ----------
template <int NOUT>
__global__ __launch_bounds__(256) void gemm_kernel(const float* __restrict__ A,
                                                   const float* __restrict__ W,
                                                   const float* __restrict__ scale,
                                                   unsigned short* __restrict__ C, int M) {
    constexpr int CG = NOUT / 4;    // float4 column groups
    constexpr int RG = 256 / CG;
    constexpr int RPT = 32 / RG;

    __shared__ float sW[128 * NOUT];
    __shared__ float sA[32 * 128];

    int tid = threadIdx.x;
    int cg = tid % CG;
    int rg = tid / CG;
    int row0 = blockIdx.x * 32;

    for (int i = tid; i < 128 * NOUT / 4; i += 256)
        ((float4*)sW)[i] = ((const float4*)W)[i];
    for (int i = tid; i < 32 * 128 / 4; i += 256) {
        int r = i >> 5;
        int c = i & 31;
        int gr = row0 + r;
        float4 v = make_float4(0.f, 0.f, 0.f, 0.f);
        if (gr < M) v = ((const float4*)(A + (size_t)gr * 128))[c];
        ((float4*)sA)[i] = v;
    }
    __syncthreads();

    float acc[RPT][4] = {};
#pragma unroll 4
    for (int k4 = 0; k4 < 32; ++k4) {
        float4 a[RPT];
#pragma unroll
        for (int r = 0; r < RPT; ++r)
            a[r] = ((float4*)(sA + (rg * RPT + r) * 128))[k4];
#pragma unroll
        for (int kk = 0; kk < 4; ++kk) {
            float4 w = ((float4*)sW)[(k4 * 4 + kk) * CG + cg];
#pragma unroll
            for (int r = 0; r < RPT; ++r) {
                float av = (kk == 0) ? a[r].x : (kk == 1) ? a[r].y : (kk == 2) ? a[r].z : a[r].w;
                acc[r][0] += av * w.x;
                acc[r][1] += av * w.y;
                acc[r][2] += av * w.z;
                acc[r][3] += av * w.w;
            }
        }
    }
    for (int r = 0; r < RPT; ++r) {
        int gr = row0 + rg * RPT + r;
        if (gr < M) {
            float sc = scale[gr];
            ushort4 o;
            o.x = f2bf(acc[r][0] * sc);
            o.y = f2bf(acc[r][1] * sc);
            o.z = f2bf(acc[r][2] * sc);
            o.w = f2bf(acc[r][3] * sc);
            *((ushort4*)(C + (size_t)gr * NOUT) + cg) = o;
        }
    }
}

// ---------- Gather aggregation (bf16 pre-scaled rows): one wave per node ----------
// h[n] = relu(dd*(tp[n] + sum tp[s]) + bias)
__global__ __launch_bounds__(256) void aggregate128_kernel(
    const int* __restrict__ rowoff, const int* __restrict__ csr_src,
    const float* __restrict__ dis, const unsigned short* __restrict__ tp,
    const float* __restrict__ bias, float* __restrict__ hout, int n) {
    int node = (blockIdx.x * 256 + threadIdx.x) >> 6;
    int lane = threadIdx.x & 63;
    if (node >= n) return;
    float dd = dis[node];
    const ushort2* base = (const ushort2*)tp + lane;  // row stride = 64 ushort2
    ushort2 self = base[(size_t)node * 64];
    float ax = bf2f(self.x), ay = bf2f(self.y);
    int beg = rowoff[node], end = rowoff[node + 1];
    int i = beg;
    for (; i + 4 <= end; i += 4) {
        int s0 = csr_src[i], s1 = csr_src[i + 1], s2 = csr_src[i + 2], s3 = csr_src[i + 3];
        ushort2 u0 = base[(size_t)s0 * 64];
        ushort2 u1 = base[(size_t)s1 * 64];
        ushort2 u2 = base[(size_t)s2 * 64];
        ushort2 u3 = base[(size_t)s3 * 64];
        ax += (bf2f(u0.x) + bf2f(u1.x)) + (bf2f(u2.x) + bf2f(u3.x));
        ay += (bf2f(u0.y) + bf2f(u1.y)) + (bf2f(u2.y) + bf2f(u3.y));
    }
    for (; i < end; ++i) {
        ushort2 u = base[(size_t)csr_src[i] * 64];
        ax += bf2f(u.x);
        ay += bf2f(u.y);
    }
    float2 b = ((const float2*)bias)[lane];
    ax = fmaxf(ax * dd + b.x, 0.f);
    ay = fmaxf(ay * dd + b.y, 0.f);
    ((float2*)hout)[(size_t)node * 64 + lane] = make_float2(ax, ay);
}

// F=64, no relu, fused head: h3 = dd*(tp[n]+sum tp[s]) + b2 ; out = h3@Wout + bout
__global__ __launch_bounds__(256) void aggregate64_head_kernel(
    const int* __restrict__ rowoff, const int* __restrict__ csr_src,
    const float* __restrict__ dis, const unsigned short* __restrict__ tp,
    const float* __restrict__ bias, const float* __restrict__ Wout,
    const float* __restrict__ bout, float* __restrict__ hout,
    float* __restrict__ out, int n) {
    int node = (blockIdx.x * 256 + threadIdx.x) >> 6;
    int lane = threadIdx.x & 63;
    if (node >= n) return;
    float dd = dis[node];
    const unsigned short* base = tp + lane;  // row stride = 64
    float acc = bf2f(base[(size_t)node * 64]);
    int beg = rowoff[node], end = rowoff[node + 1];
    int i = beg;
    for (; i + 4 <= end; i += 4) {
        int s0 = csr_src[i], s1 = csr_src[i + 1], s2 = csr_src[i + 2], s3 = csr_src[i + 3];
        float v0 = bf2f(base[(size_t)s0 * 64]);
        float v1 = bf2f(base[(size_t)s1 * 64]);
        float v2 = bf2f(base[(size_t)s2 * 64]);
        float v3 = bf2f(base[(size_t)s3 * 64]);
        acc += (v0 + v1) + (v2 + v3);
    }
    for (; i < end; ++i) acc += bf2f(base[(size_t)csr_src[i] * 64]);
    acc = acc * dd + bias[lane];
    hout[(size_t)node * 64 + lane] = acc;
    float p = acc * Wout[lane];
#pragma unroll
    for (int off = 32; off > 0; off >>= 1) p += __shfl_down(p, off);
    if (lane == 0) out[node] = p + bout[0];
}

extern "C" void kernel_launch(void* const* d_in, const int* in_sizes, int n_in,
                              void* d_out, int out_size, void* d_ws, size_t ws_size,
                              hipStream_t stream) {
    const float* x    = (const float*)d_in[0];
    const int*   ei   = (const int*)d_in[1];  // [2, E] flat: src then dst
    const float* W1   = (const float*)d_in[2];
    const float* b1   = (const float*)d_in[3];
    const float* Wh   = (const float*)d_in[4];
    const float* bh   = (const float*)d_in[5];
    const float* W2   = (const float*)d_in[6];
    const float* b2   = (const float*)d_in[7];
    const float* Wout = (const float*)d_in[8];
    const float* bout = (const float*)d_in[9];

    const int N = N_NODES;
    const int E = N_EDGES;
    const int NB = (N + 255) / 256;  // 196 blocks
    const int* srcv = ei;
    const int* dstv = ei + E;

    float* out  = (float*)d_out;            // [N]
    float* hout = (float*)d_out + N;        // [N x 64]

    char* ws = (char*)d_ws;
    int*   cnt     = (int*)ws;                          ws += sizeof(int) * N;
    int*   rowoff  = (int*)ws;                          ws += sizeof(int) * (N + 1);
    int*   cursor  = (int*)ws;                          ws += sizeof(int) * N;
    int*   bsum    = (int*)ws;                          ws += sizeof(int) * 256;
    int*   boff    = (int*)ws;                          ws += sizeof(int) * 256;
    int*   csr_src = (int*)ws;                          ws += sizeof(int) * E;
    float* dis     = (float*)ws;                        ws += sizeof(float) * N;
    unsigned short* bufT = (unsigned short*)ws;         ws += sizeof(unsigned short) * (size_t)N * 128;
    float* bufH    = (float*)ws;                        // N*128 fp32

    // --- CSR build + normalization ---
    hipMemsetAsync(cnt, 0, sizeof(int) * N, stream);
    count_kernel<<<(E + 255) / 256, 256, 0, stream>>>(dstv, cnt, E);
    scan_bsum_kernel<<<NB, 256, 0, stream>>>(cnt, bsum, N);
    scan_boff_kernel<<<1, 256, 0, stream>>>(bsum, boff, rowoff + N, NB);
    scan_apply_kernel<<<NB, 256, 0, stream>>>(cnt, boff, rowoff, cursor, dis, N);
    fill_kernel<<<(E + 255) / 256, 256, 0, stream>>>(srcv, dstv, cursor, csr_src, E);

    // --- layer 1: h1 = relu(agg(x@W1) + b1) ---
    gemm_kernel<128><<<(N + 31) / 32, 256, 0, stream>>>(x, W1, dis, bufT, N);
    aggregate128_kernel<<<((size_t)N * 64 + 255) / 256, 256, 0, stream>>>(
        rowoff, csr_src, dis, bufT, b1, bufH, N);

    // --- layer 2: h2 = relu(agg(h1@Wh) + bh) ---
    gemm_kernel<128><<<(N + 31) / 32, 256, 0, stream>>>(bufH, Wh, dis, bufT, N);
    aggregate128_kernel<<<((size_t)N * 64 + 255) / 256, 256, 0, stream>>>(
        rowoff, csr_src, dis, bufT, bh, bufH, N);

    // --- layer 3 + head: h3 = agg(h2@W2) + b2 ; out = h3@Wout + bout ---
    gemm_kernel<64><<<(N + 31) / 32, 256, 0, stream>>>(bufH, W2, dis, bufT, N);
    aggregate64_head_kernel<<<((size_t)N * 64 + 255) / 256, 256, 0, stream>>>(
        rowoff, csr_src, dis, bufT, b2, Wout, bout, hout, out, N);
}

// Round 5
// 392.012 us; speedup vs baseline: 9.1366x; 1.0276x over previous
//
#include <hip/hip_runtime.h>
#include <hip/hip_bf16.h>

// GCN: 3x GCNConv (sym-norm, self-loops) + linear head.
// N=50000 nodes, E=800000 edges, F: 128 -> 128 -> 128 -> 64 -> 1.
// Round 5:
//  - GEMM col-split (32 rows x 64 cols/block): LDS 80 KB -> 48 KB, 3 blocks/CU
//    (was 1.3) so ds_read latency is hidden; W staging per block halves.
//  - aggregate128: 2 nodes per wave, interleaved unroll-4 gather streams
//    (8 outstanding 256 B gathers/wave instead of 4) for the latency-bound gather.
// CSR build (count/scan/fill) unchanged; fill's 52 us (64 B write-allocate
// amplification) is the next target if it remains top.

#define N_NODES 50000
#define N_EDGES 800000

static __device__ __forceinline__ unsigned short f2bf(float f) {
    __hip_bfloat16 h = __float2bfloat16(f);  // RNE
    return *reinterpret_cast<unsigned short*>(&h);
}
static __device__ __forceinline__ float bf2f(unsigned short u) {
    return __uint_as_float(((unsigned)u) << 16);  // exact
}

// ---------- CSR build ----------

__global__ __launch_bounds__(256) void count_kernel(const int* __restrict__ dst,
                                                    int* __restrict__ cnt, int nE) {
    int i = blockIdx.x * 256 + threadIdx.x;
    if (i < nE) atomicAdd(&cnt[dst[i]], 1);
}

__global__ __launch_bounds__(256) void scan_bsum_kernel(const int* __restrict__ cnt,
                                                        int* __restrict__ bsum, int n) {
    int i = blockIdx.x * 256 + threadIdx.x;
    int v = (i < n) ? cnt[i] : 0;
#pragma unroll
    for (int off = 32; off > 0; off >>= 1) v += __shfl_down(v, off);
    __shared__ int wsum[4];
    int lane = threadIdx.x & 63, w = threadIdx.x >> 6;
    if (lane == 0) wsum[w] = v;
    __syncthreads();
    if (threadIdx.x == 0) bsum[blockIdx.x] = wsum[0] + wsum[1] + wsum[2] + wsum[3];
}

__global__ __launch_bounds__(256) void scan_boff_kernel(const int* __restrict__ bsum,
                                                        int* __restrict__ boff,
                                                        int* __restrict__ rowoff_last,
                                                        int nb) {
    __shared__ int s[256];
    int tid = threadIdx.x;
    int v = (tid < nb) ? bsum[tid] : 0;
    s[tid] = v;
    __syncthreads();
    for (int off = 1; off < 256; off <<= 1) {
        int t = (tid >= off) ? s[tid - off] : 0;
        __syncthreads();
        s[tid] += t;
        __syncthreads();
    }
    if (tid < nb) boff[tid] = s[tid] - v;           // exclusive
    if (tid == 255) *rowoff_last = s[255];          // total == E
}

__global__ __launch_bounds__(256) void scan_apply_kernel(const int* __restrict__ cnt,
                                                         const int* __restrict__ boff,
                                                         int* __restrict__ rowoff,
                                                         int* __restrict__ cursor,
                                                         float* __restrict__ dis, int n) {
    __shared__ int s[256];
    int tid = threadIdx.x;
    int i = blockIdx.x * 256 + tid;
    int v = (i < n) ? cnt[i] : 0;
    s[tid] = v;
    __syncthreads();
    for (int off = 1; off < 256; off <<= 1) {
        int t = (tid >= off) ? s[tid - off] : 0;
        __syncthreads();
        s[tid] += t;
        __syncthreads();
    }
    if (i < n) {
        int ex = boff[blockIdx.x] + s[tid] - v;
        rowoff[i] = ex;
        cursor[i] = ex;
        dis[i] = rsqrtf((float)(v + 1));  // +1 self-loop
    }
}

__global__ __launch_bounds__(256) void fill_kernel(const int* __restrict__ srcv,
                                                   const int* __restrict__ dstv,
                                                   int* __restrict__ cursor,
                                                   int* __restrict__ csr_src, int nE) {
    int i = blockIdx.x * 256 + threadIdx.x;
    if (i < nE) {
        int d = dstv[i];
        int pos = atomicAdd(&cursor[d], 1);
        csr_src[pos] = srcv[i];
    }
}

// ---------- GEMM: C[r] = bf16((A[r] @ W) * scale[r]) ----------
// Col-split: block = 32 rows x 64 cols. LDS = 32 KB sW + 16 KB sA = 48 KB
// -> 3 blocks/CU. grid.y indexes the 64-col slab.
template <int NOUT>
__global__ __launch_bounds__(256) void gemm_kernel(const float* __restrict__ A,
                                                   const float* __restrict__ W,
                                                   const float* __restrict__ scale,
                                                   unsigned short* __restrict__ C, int M) {
    __shared__ float sW[128 * 64];
    __shared__ float sA[32 * 128];

    int tid = threadIdx.x;
    int cg = tid & 15;        // float4 col group within the 64-col slab
    int rg = tid >> 4;        // 16 row groups -> RPT = 2
    int row0 = blockIdx.x * 32;
    int col0 = blockIdx.y * 64;

    // stage W slab: W[k][col0 + 0..63], k = 0..127
    for (int i = tid; i < 128 * 16; i += 256) {
        int k = i >> 4;
        int c = i & 15;
        ((float4*)sW)[i] = *((const float4*)(W + (size_t)k * NOUT + col0) + c);
    }
    // stage A tile (32 rows x 128)
    for (int i = tid; i < 32 * 32; i += 256) {
        int r = i >> 5;
        int c = i & 31;
        int gr = row0 + r;
        float4 v = make_float4(0.f, 0.f, 0.f, 0.f);
        if (gr < M) v = ((const float4*)(A + (size_t)gr * 128))[c];
        ((float4*)sA)[i] = v;
    }
    __syncthreads();

    float acc[2][4] = {};
#pragma unroll 4
    for (int k4 = 0; k4 < 32; ++k4) {
        float4 a0 = ((float4*)(sA + (rg * 2 + 0) * 128))[k4];
        float4 a1 = ((float4*)(sA + (rg * 2 + 1) * 128))[k4];
#pragma unroll
        for (int kk = 0; kk < 4; ++kk) {
            float4 w = ((float4*)sW)[(k4 * 4 + kk) * 16 + cg];
            float av0 = (kk == 0) ? a0.x : (kk == 1) ? a0.y : (kk == 2) ? a0.z : a0.w;
            float av1 = (kk == 0) ? a1.x : (kk == 1) ? a1.y : (kk == 2) ? a1.z : a1.w;
            acc[0][0] += av0 * w.x; acc[0][1] += av0 * w.y;
            acc[0][2] += av0 * w.z; acc[0][3] += av0 * w.w;
            acc[1][0] += av1 * w.x; acc[1][1] += av1 * w.y;
            acc[1][2] += av1 * w.z; acc[1][3] += av1 * w.w;
        }
    }
#pragma unroll
    for (int r = 0; r < 2; ++r) {
        int gr = row0 + rg * 2 + r;
        if (gr < M) {
            float sc = scale[gr];
            ushort4 o;
            o.x = f2bf(acc[r][0] * sc);
            o.y = f2bf(acc[r][1] * sc);
            o.z = f2bf(acc[r][2] * sc);
            o.w = f2bf(acc[r][3] * sc);
            *((ushort4*)(C + (size_t)gr * NOUT + col0) + cg) = o;
        }
    }
}

// ---------- Gather aggregation (bf16 rows): 2 nodes per wave ----------
// h[n] = relu(dd*(tp[n] + sum tp[s]) + bias)
__global__ __launch_bounds__(256) void aggregate128_kernel(
    const int* __restrict__ rowoff, const int* __restrict__ csr_src,
    const float* __restrict__ dis, const unsigned short* __restrict__ tp,
    const float* __restrict__ bias, float* __restrict__ hout, int n) {
    int wid = (blockIdx.x * 256 + threadIdx.x) >> 6;
    int lane = threadIdx.x & 63;
    int n0 = wid * 2;
    if (n0 >= n) return;
    int n1 = n0 + 1;
    bool has1 = (n1 < n);
    const ushort2* base = (const ushort2*)tp + lane;  // row stride = 64 ushort2

    float dd0 = dis[n0];
    int beg0 = rowoff[n0];
    int mid  = rowoff[n0 + 1];
    int end1 = has1 ? rowoff[n1 + 1] : mid;
    float dd1 = has1 ? dis[n1] : 0.f;

    ushort2 s0 = base[(size_t)n0 * 64];
    float a0x = bf2f(s0.x), a0y = bf2f(s0.y);
    float a1x = 0.f, a1y = 0.f;
    if (has1) {
        ushort2 s1 = base[(size_t)n1 * 64];
        a1x = bf2f(s1.x);
        a1y = bf2f(s1.y);
    }

    int i0 = beg0, i1 = mid;
    // joint phase: 8 gathers in flight
    while (i0 + 4 <= mid && i1 + 4 <= end1) {
        int p0 = csr_src[i0], p1 = csr_src[i0 + 1], p2 = csr_src[i0 + 2], p3 = csr_src[i0 + 3];
        int q0 = csr_src[i1], q1 = csr_src[i1 + 1], q2 = csr_src[i1 + 2], q3 = csr_src[i1 + 3];
        ushort2 u0 = base[(size_t)p0 * 64], u1 = base[(size_t)p1 * 64];
        ushort2 u2 = base[(size_t)p2 * 64], u3 = base[(size_t)p3 * 64];
        ushort2 v0 = base[(size_t)q0 * 64], v1 = base[(size_t)q1 * 64];
        ushort2 v2 = base[(size_t)q2 * 64], v3 = base[(size_t)q3 * 64];
        a0x += (bf2f(u0.x) + bf2f(u1.x)) + (bf2f(u2.x) + bf2f(u3.x));
        a0y += (bf2f(u0.y) + bf2f(u1.y)) + (bf2f(u2.y) + bf2f(u3.y));
        a1x += (bf2f(v0.x) + bf2f(v1.x)) + (bf2f(v2.x) + bf2f(v3.x));
        a1y += (bf2f(v0.y) + bf2f(v1.y)) + (bf2f(v2.y) + bf2f(v3.y));
        i0 += 4;
        i1 += 4;
    }
    // drain node0
    for (; i0 + 4 <= mid; i0 += 4) {
        int p0 = csr_src[i0], p1 = csr_src[i0 + 1], p2 = csr_src[i0 + 2], p3 = csr_src[i0 + 3];
        ushort2 u0 = base[(size_t)p0 * 64], u1 = base[(size_t)p1 * 64];
        ushort2 u2 = base[(size_t)p2 * 64], u3 = base[(size_t)p3 * 64];
        a0x += (bf2f(u0.x) + bf2f(u1.x)) + (bf2f(u2.x) + bf2f(u3.x));
        a0y += (bf2f(u0.y) + bf2f(u1.y)) + (bf2f(u2.y) + bf2f(u3.y));
    }
    for (; i0 < mid; ++i0) {
        ushort2 u = base[(size_t)csr_src[i0] * 64];
        a0x += bf2f(u.x);
        a0y += bf2f(u.y);
    }
    // drain node1
    for (; i1 + 4 <= end1; i1 += 4) {
        int q0 = csr_src[i1], q1 = csr_src[i1 + 1], q2 = csr_src[i1 + 2], q3 = csr_src[i1 + 3];
        ushort2 v0 = base[(size_t)q0 * 64], v1 = base[(size_t)q1 * 64];
        ushort2 v2 = base[(size_t)q2 * 64], v3 = base[(size_t)q3 * 64];
        a1x += (bf2f(v0.x) + bf2f(v1.x)) + (bf2f(v2.x) + bf2f(v3.x));
        a1y += (bf2f(v0.y) + bf2f(v1.y)) + (bf2f(v2.y) + bf2f(v3.y));
    }
    for (; i1 < end1; ++i1) {
        ushort2 v = base[(size_t)csr_src[i1] * 64];
        a1x += bf2f(v.x);
        a1y += bf2f(v.y);
    }

    float2 b = ((const float2*)bias)[lane];
    float r0x = fmaxf(a0x * dd0 + b.x, 0.f);
    float r0y = fmaxf(a0y * dd0 + b.y, 0.f);
    ((float2*)hout)[(size_t)n0 * 64 + lane] = make_float2(r0x, r0y);
    if (has1) {
        float r1x = fmaxf(a1x * dd1 + b.x, 0.f);
        float r1y = fmaxf(a1y * dd1 + b.y, 0.f);
        ((float2*)hout)[(size_t)n1 * 64 + lane] = make_float2(r1x, r1y);
    }
}

// F=64, no relu, fused head: h3 = dd*(tp[n]+sum tp[s]) + b2 ; out = h3@Wout + bout
__global__ __launch_bounds__(256) void aggregate64_head_kernel(
    const int* __restrict__ rowoff, const int* __restrict__ csr_src,
    const float* __restrict__ dis, const unsigned short* __restrict__ tp,
    const float* __restrict__ bias, const float* __restrict__ Wout,
    const float* __restrict__ bout, float* __restrict__ hout,
    float* __restrict__ out, int n) {
    int node = (blockIdx.x * 256 + threadIdx.x) >> 6;
    int lane = threadIdx.x & 63;
    if (node >= n) return;
    float dd = dis[node];
    const unsigned short* base = tp + lane;  // row stride = 64
    float acc = bf2f(base[(size_t)node * 64]);
    int beg = rowoff[node], end = rowoff[node + 1];
    int i = beg;
    for (; i + 4 <= end; i += 4) {
        int s0 = csr_src[i], s1 = csr_src[i + 1], s2 = csr_src[i + 2], s3 = csr_src[i + 3];
        float v0 = bf2f(base[(size_t)s0 * 64]);
        float v1 = bf2f(base[(size_t)s1 * 64]);
        float v2 = bf2f(base[(size_t)s2 * 64]);
        float v3 = bf2f(base[(size_t)s3 * 64]);
        acc += (v0 + v1) + (v2 + v3);
    }
    for (; i < end; ++i) acc += bf2f(base[(size_t)csr_src[i] * 64]);
    acc = acc * dd + bias[lane];
    hout[(size_t)node * 64 + lane] = acc;
    float p = acc * Wout[lane];
#pragma unroll
    for (int off = 32; off > 0; off >>= 1) p += __shfl_down(p, off);
    if (lane == 0) out[node] = p + bout[0];
}

extern "C" void kernel_launch(void* const* d_in, const int* in_sizes, int n_in,
                              void* d_out, int out_size, void* d_ws, size_t ws_size,
                              hipStream_t stream) {
    const float* x    = (const float*)d_in[0];
    const int*   ei   = (const int*)d_in[1];  // [2, E] flat: src then dst
    const float* W1   = (const float*)d_in[2];
    const float* b1   = (const float*)d_in[3];
    const float* Wh   = (const float*)d_in[4];
    const float* bh   = (const float*)d_in[5];
    const float* W2   = (const float*)d_in[6];
    const float* b2   = (const float*)d_in[7];
    const float* Wout = (const float*)d_in[8];
    const float* bout = (const float*)d_in[9];

    const int N = N_NODES;
    const int E = N_EDGES;
    const int NB = (N + 255) / 256;  // 196 blocks
    const int* srcv = ei;
    const int* dstv = ei + E;

    float* out  = (float*)d_out;            // [N]
    float* hout = (float*)d_out + N;        // [N x 64]

    char* ws = (char*)d_ws;
    int*   cnt     = (int*)ws;                          ws += sizeof(int) * N;
    int*   rowoff  = (int*)ws;                          ws += sizeof(int) * (N + 1);
    int*   cursor  = (int*)ws;                          ws += sizeof(int) * N;
    int*   bsum    = (int*)ws;                          ws += sizeof(int) * 256;
    int*   boff    = (int*)ws;                          ws += sizeof(int) * 256;
    int*   csr_src = (int*)ws;                          ws += sizeof(int) * E;
    float* dis     = (float*)ws;                        ws += sizeof(float) * N;
    unsigned short* bufT = (unsigned short*)ws;         ws += sizeof(unsigned short) * (size_t)N * 128;
    float* bufH    = (float*)ws;                        // N*128 fp32

    // --- CSR build + normalization ---
    hipMemsetAsync(cnt, 0, sizeof(int) * N, stream);
    count_kernel<<<(E + 255) / 256, 256, 0, stream>>>(dstv, cnt, E);
    scan_bsum_kernel<<<NB, 256, 0, stream>>>(cnt, bsum, N);
    scan_boff_kernel<<<1, 256, 0, stream>>>(bsum, boff, rowoff + N, NB);
    scan_apply_kernel<<<NB, 256, 0, stream>>>(cnt, boff, rowoff, cursor, dis, N);
    fill_kernel<<<(E + 255) / 256, 256, 0, stream>>>(srcv, dstv, cursor, csr_src, E);

    const int aggBlocks = ((N + 1) / 2 * 64 + 255) / 256;  // 2 nodes per wave

    // --- layer 1: h1 = relu(agg(x@W1) + b1) ---
    gemm_kernel<128><<<dim3((N + 31) / 32, 2), 256, 0, stream>>>(x, W1, dis, bufT, N);
    aggregate128_kernel<<<aggBlocks, 256, 0, stream>>>(rowoff, csr_src, dis, bufT, b1, bufH, N);

    // --- layer 2: h2 = relu(agg(h1@Wh) + bh) ---
    gemm_kernel<128><<<dim3((N + 31) / 32, 2), 256, 0, stream>>>(bufH, Wh, dis, bufT, N);
    aggregate128_kernel<<<aggBlocks, 256, 0, stream>>>(rowoff, csr_src, dis, bufT, bh, bufH, N);

    // --- layer 3 + head: h3 = agg(h2@W2) + b2 ; out = h3@Wout + bout ---
    gemm_kernel<64><<<dim3((N + 31) / 32, 1), 256, 0, stream>>>(bufH, W2, dis, bufT, N);
    aggregate64_head_kernel<<<((size_t)N * 64 + 255) / 256, 256, 0, stream>>>(
        rowoff, csr_src, dis, bufT, b2, Wout, bout, hout, out, N);
}

// Round 6
// 380.181 us; speedup vs baseline: 9.4210x; 1.0311x over previous
//
#include <hip/hip_runtime.h>
#include <hip/hip_bf16.h>

// GCN: 3x GCNConv (sym-norm, self-loops) + linear head.
// N=50000 nodes, E=800000 edges, F: 128 -> 128 -> 128 -> 64 -> 1.
// Round 6: CSR build rewritten as two-level LDS-bucketed counting sort.
// Old build (count + scan + fill) did 1.6M random device-scope atomics and
// 800k random 4 B stores -> 51.7 MB HBM writes (16x line amplification),
// fill alone 53 us. New build:
//   hist (LDS 196-bucket histogram, no global atomics)
//   scanH (1 block scans 196x196 offsets)
//   partition (contiguous per-(bucket,block) runs of (src,dst) pairs, ~1.3x amp)
//   bucket_csr (per-bucket block: LDS count+scan -> rowoff/dis, scatter into
//               block-owned 16 KB slice -> full-line writes, LDS-only atomics)
// GEMM (col-split, bf16 out) and gather-aggregates unchanged from round 5.

#define N_NODES 50000
#define N_EDGES 800000
#define NBUCK 196          // ceil(N/256) coarse buckets (dst>>8)
#define GB 196             // edge-chunk blocks
#define EPB 4096           // edges per block (GB*EPB >= E)

static __device__ __forceinline__ unsigned short f2bf(float f) {
    __hip_bfloat16 h = __float2bfloat16(f);  // RNE
    return *reinterpret_cast<unsigned short*>(&h);
}
static __device__ __forceinline__ float bf2f(unsigned short u) {
    return __uint_as_float(((unsigned)u) << 16);  // exact
}

// ---------- CSR build: two-level counting sort ----------

__global__ __launch_bounds__(256) void hist_kernel(const int* __restrict__ dstv,
                                                   int* __restrict__ H, int nE) {
    __shared__ int h[NBUCK];
    for (int i = threadIdx.x; i < NBUCK; i += 256) h[i] = 0;
    __syncthreads();
    int base = blockIdx.x * EPB;
#pragma unroll
    for (int i = 0; i < EPB / 256; ++i) {
        int e = base + i * 256 + threadIdx.x;
        if (e < nE) atomicAdd(&h[dstv[e] >> 8], 1);
    }
    __syncthreads();
    for (int i = threadIdx.x; i < NBUCK; i += 256)
        H[i * GB + blockIdx.x] = h[i];   // bucket-major
}

// Exclusive scan of H (NBUCK*GB, bucket-major) in place; bstart[k] = offset of
// bucket k's first element; rowoff[N] = E.
__global__ __launch_bounds__(1024) void scanH_kernel(int* __restrict__ H,
                                                     int* __restrict__ bstart,
                                                     int* __restrict__ rowoff_last) {
    const int L = NBUCK * GB;
    const int PT = (L + 1023) / 1024;  // 38
    __shared__ int s[1024];
    int t = threadIdx.x;
    int lo = t * PT, hi = min(L, lo + PT);
    int sum = 0;
    for (int i = lo; i < hi; ++i) sum += H[i];
    s[t] = sum;
    __syncthreads();
    for (int off = 1; off < 1024; off <<= 1) {
        int v = (t >= off) ? s[t - off] : 0;
        __syncthreads();
        s[t] += v;
        __syncthreads();
    }
    int run = s[t] - sum;  // exclusive base for this thread's stripe
    for (int i = lo; i < hi; ++i) {
        int v = H[i];
        H[i] = run;
        if ((i % GB) == 0) bstart[i / GB] = run;
        run += v;
    }
    if (t == 0) {
        bstart[NBUCK] = N_EDGES;
        *rowoff_last = N_EDGES;
    }
}

// Scatter (src,dst) pairs into bucket-partitioned P; per-(bucket,block) runs
// are contiguous so stores stay dense.
__global__ __launch_bounds__(256) void partition_kernel(const int* __restrict__ srcv,
                                                        const int* __restrict__ dstv,
                                                        const int* __restrict__ H,
                                                        int2* __restrict__ P, int nE) {
    __shared__ int cur[NBUCK];
    for (int i = threadIdx.x; i < NBUCK; i += 256) cur[i] = H[i * GB + blockIdx.x];
    __syncthreads();
    int base = blockIdx.x * EPB;
#pragma unroll
    for (int i = 0; i < EPB / 256; ++i) {
        int e = base + i * 256 + threadIdx.x;
        if (e < nE) {
            int d = dstv[e];
            int sv = srcv[e];
            int pos = atomicAdd(&cur[d >> 8], 1);
            P[pos] = make_int2(sv, d);
        }
    }
}

// One block per bucket: 256 nodes, block-owned csr_src slice.
__global__ __launch_bounds__(256) void bucket_csr_kernel(const int2* __restrict__ P,
                                                         const int* __restrict__ bstart,
                                                         int* __restrict__ rowoff,
                                                         float* __restrict__ dis,
                                                         int* __restrict__ csr_src, int n) {
    __shared__ int cnt[256];
    __shared__ int s[256];
    __shared__ int cur[256];
    int t = threadIdx.x;
    int k = blockIdx.x;
    int ebeg = bstart[k], eend = bstart[k + 1];
    cnt[t] = 0;
    __syncthreads();
    for (int e = ebeg + t; e < eend; e += 256)
        atomicAdd(&cnt[P[e].y & 255], 1);
    __syncthreads();
    int myc = cnt[t];
    s[t] = myc;
    __syncthreads();
    for (int off = 1; off < 256; off <<= 1) {
        int v = (t >= off) ? s[t - off] : 0;
        __syncthreads();
        s[t] += v;
        __syncthreads();
    }
    int excl = s[t] - myc;
    int node = (k << 8) + t;
    if (node < n) {
        rowoff[node] = ebeg + excl;
        dis[node] = rsqrtf((float)(myc + 1));  // +1 self-loop
    }
    cur[t] = ebeg + excl;
    __syncthreads();
    for (int e = ebeg + t; e < eend; e += 256) {
        int2 p = P[e];
        int pos = atomicAdd(&cur[p.y & 255], 1);
        csr_src[pos] = p.x;
    }
}

// ---------- GEMM: C[r] = bf16((A[r] @ W) * scale[r]) ----------
// Col-split: block = 32 rows x 64 cols. LDS = 48 KB -> 3 blocks/CU.
template <int NOUT>
__global__ __launch_bounds__(256) void gemm_kernel(const float* __restrict__ A,
                                                   const float* __restrict__ W,
                                                   const float* __restrict__ scale,
                                                   unsigned short* __restrict__ C, int M) {
    __shared__ float sW[128 * 64];
    __shared__ float sA[32 * 128];

    int tid = threadIdx.x;
    int cg = tid & 15;
    int rg = tid >> 4;
    int row0 = blockIdx.x * 32;
    int col0 = blockIdx.y * 64;

    for (int i = tid; i < 128 * 16; i += 256) {
        int k = i >> 4;
        int c = i & 15;
        ((float4*)sW)[i] = *((const float4*)(W + (size_t)k * NOUT + col0) + c);
    }
    for (int i = tid; i < 32 * 32; i += 256) {
        int r = i >> 5;
        int c = i & 31;
        int gr = row0 + r;
        float4 v = make_float4(0.f, 0.f, 0.f, 0.f);
        if (gr < M) v = ((const float4*)(A + (size_t)gr * 128))[c];
        ((float4*)sA)[i] = v;
    }
    __syncthreads();

    float acc[2][4] = {};
#pragma unroll 4
    for (int k4 = 0; k4 < 32; ++k4) {
        float4 a0 = ((float4*)(sA + (rg * 2 + 0) * 128))[k4];
        float4 a1 = ((float4*)(sA + (rg * 2 + 1) * 128))[k4];
#pragma unroll
        for (int kk = 0; kk < 4; ++kk) {
            float4 w = ((float4*)sW)[(k4 * 4 + kk) * 16 + cg];
            float av0 = (kk == 0) ? a0.x : (kk == 1) ? a0.y : (kk == 2) ? a0.z : a0.w;
            float av1 = (kk == 0) ? a1.x : (kk == 1) ? a1.y : (kk == 2) ? a1.z : a1.w;
            acc[0][0] += av0 * w.x; acc[0][1] += av0 * w.y;
            acc[0][2] += av0 * w.z; acc[0][3] += av0 * w.w;
            acc[1][0] += av1 * w.x; acc[1][1] += av1 * w.y;
            acc[1][2] += av1 * w.z; acc[1][3] += av1 * w.w;
        }
    }
#pragma unroll
    for (int r = 0; r < 2; ++r) {
        int gr = row0 + rg * 2 + r;
        if (gr < M) {
            float sc = scale[gr];
            ushort4 o;
            o.x = f2bf(acc[r][0] * sc);
            o.y = f2bf(acc[r][1] * sc);
            o.z = f2bf(acc[r][2] * sc);
            o.w = f2bf(acc[r][3] * sc);
            *((ushort4*)(C + (size_t)gr * NOUT + col0) + cg) = o;
        }
    }
}

// ---------- Gather aggregation (bf16 rows): 2 nodes per wave ----------
__global__ __launch_bounds__(256) void aggregate128_kernel(
    const int* __restrict__ rowoff, const int* __restrict__ csr_src,
    const float* __restrict__ dis, const unsigned short* __restrict__ tp,
    const float* __restrict__ bias, float* __restrict__ hout, int n) {
    int wid = (blockIdx.x * 256 + threadIdx.x) >> 6;
    int lane = threadIdx.x & 63;
    int n0 = wid * 2;
    if (n0 >= n) return;
    int n1 = n0 + 1;
    bool has1 = (n1 < n);
    const ushort2* base = (const ushort2*)tp + lane;

    float dd0 = dis[n0];
    int beg0 = rowoff[n0];
    int mid  = rowoff[n0 + 1];
    int end1 = has1 ? rowoff[n1 + 1] : mid;
    float dd1 = has1 ? dis[n1] : 0.f;

    ushort2 s0 = base[(size_t)n0 * 64];
    float a0x = bf2f(s0.x), a0y = bf2f(s0.y);
    float a1x = 0.f, a1y = 0.f;
    if (has1) {
        ushort2 s1 = base[(size_t)n1 * 64];
        a1x = bf2f(s1.x);
        a1y = bf2f(s1.y);
    }

    int i0 = beg0, i1 = mid;
    while (i0 + 4 <= mid && i1 + 4 <= end1) {
        int p0 = csr_src[i0], p1 = csr_src[i0 + 1], p2 = csr_src[i0 + 2], p3 = csr_src[i0 + 3];
        int q0 = csr_src[i1], q1 = csr_src[i1 + 1], q2 = csr_src[i1 + 2], q3 = csr_src[i1 + 3];
        ushort2 u0 = base[(size_t)p0 * 64], u1 = base[(size_t)p1 * 64];
        ushort2 u2 = base[(size_t)p2 * 64], u3 = base[(size_t)p3 * 64];
        ushort2 v0 = base[(size_t)q0 * 64], v1 = base[(size_t)q1 * 64];
        ushort2 v2 = base[(size_t)q2 * 64], v3 = base[(size_t)q3 * 64];
        a0x += (bf2f(u0.x) + bf2f(u1.x)) + (bf2f(u2.x) + bf2f(u3.x));
        a0y += (bf2f(u0.y) + bf2f(u1.y)) + (bf2f(u2.y) + bf2f(u3.y));
        a1x += (bf2f(v0.x) + bf2f(v1.x)) + (bf2f(v2.x) + bf2f(v3.x));
        a1y += (bf2f(v0.y) + bf2f(v1.y)) + (bf2f(v2.y) + bf2f(v3.y));
        i0 += 4;
        i1 += 4;
    }
    for (; i0 + 4 <= mid; i0 += 4) {
        int p0 = csr_src[i0], p1 = csr_src[i0 + 1], p2 = csr_src[i0 + 2], p3 = csr_src[i0 + 3];
        ushort2 u0 = base[(size_t)p0 * 64], u1 = base[(size_t)p1 * 64];
        ushort2 u2 = base[(size_t)p2 * 64], u3 = base[(size_t)p3 * 64];
        a0x += (bf2f(u0.x) + bf2f(u1.x)) + (bf2f(u2.x) + bf2f(u3.x));
        a0y += (bf2f(u0.y) + bf2f(u1.y)) + (bf2f(u2.y) + bf2f(u3.y));
    }
    for (; i0 < mid; ++i0) {
        ushort2 u = base[(size_t)csr_src[i0] * 64];
        a0x += bf2f(u.x);
        a0y += bf2f(u.y);
    }
    for (; i1 + 4 <= end1; i1 += 4) {
        int q0 = csr_src[i1], q1 = csr_src[i1 + 1], q2 = csr_src[i1 + 2], q3 = csr_src[i1 + 3];
        ushort2 v0 = base[(size_t)q0 * 64], v1 = base[(size_t)q1 * 64];
        ushort2 v2 = base[(size_t)q2 * 64], v3 = base[(size_t)q3 * 64];
        a1x += (bf2f(v0.x) + bf2f(v1.x)) + (bf2f(v2.x) + bf2f(v3.x));
        a1y += (bf2f(v0.y) + bf2f(v1.y)) + (bf2f(v2.y) + bf2f(v3.y));
    }
    for (; i1 < end1; ++i1) {
        ushort2 v = base[(size_t)csr_src[i1] * 64];
        a1x += bf2f(v.x);
        a1y += bf2f(v.y);
    }

    float2 b = ((const float2*)bias)[lane];
    float r0x = fmaxf(a0x * dd0 + b.x, 0.f);
    float r0y = fmaxf(a0y * dd0 + b.y, 0.f);
    ((float2*)hout)[(size_t)n0 * 64 + lane] = make_float2(r0x, r0y);
    if (has1) {
        float r1x = fmaxf(a1x * dd1 + b.x, 0.f);
        float r1y = fmaxf(a1y * dd1 + b.y, 0.f);
        ((float2*)hout)[(size_t)n1 * 64 + lane] = make_float2(r1x, r1y);
    }
}

// F=64, no relu, fused head: h3 = dd*(tp[n]+sum tp[s]) + b2 ; out = h3@Wout + bout
__global__ __launch_bounds__(256) void aggregate64_head_kernel(
    const int* __restrict__ rowoff, const int* __restrict__ csr_src,
    const float* __restrict__ dis, const unsigned short* __restrict__ tp,
    const float* __restrict__ bias, const float* __restrict__ Wout,
    const float* __restrict__ bout, float* __restrict__ hout,
    float* __restrict__ out, int n) {
    int node = (blockIdx.x * 256 + threadIdx.x) >> 6;
    int lane = threadIdx.x & 63;
    if (node >= n) return;
    float dd = dis[node];
    const unsigned short* base = tp + lane;
    float acc = bf2f(base[(size_t)node * 64]);
    int beg = rowoff[node], end = rowoff[node + 1];
    int i = beg;
    for (; i + 4 <= end; i += 4) {
        int s0 = csr_src[i], s1 = csr_src[i + 1], s2 = csr_src[i + 2], s3 = csr_src[i + 3];
        float v0 = bf2f(base[(size_t)s0 * 64]);
        float v1 = bf2f(base[(size_t)s1 * 64]);
        float v2 = bf2f(base[(size_t)s2 * 64]);
        float v3 = bf2f(base[(size_t)s3 * 64]);
        acc += (v0 + v1) + (v2 + v3);
    }
    for (; i < end; ++i) acc += bf2f(base[(size_t)csr_src[i] * 64]);
    acc = acc * dd + bias[lane];
    hout[(size_t)node * 64 + lane] = acc;
    float p = acc * Wout[lane];
#pragma unroll
    for (int off = 32; off > 0; off >>= 1) p += __shfl_down(p, off);
    if (lane == 0) out[node] = p + bout[0];
}

extern "C" void kernel_launch(void* const* d_in, const int* in_sizes, int n_in,
                              void* d_out, int out_size, void* d_ws, size_t ws_size,
                              hipStream_t stream) {
    const float* x    = (const float*)d_in[0];
    const int*   ei   = (const int*)d_in[1];  // [2, E] flat: src then dst
    const float* W1   = (const float*)d_in[2];
    const float* b1   = (const float*)d_in[3];
    const float* Wh   = (const float*)d_in[4];
    const float* bh   = (const float*)d_in[5];
    const float* W2   = (const float*)d_in[6];
    const float* b2   = (const float*)d_in[7];
    const float* Wout = (const float*)d_in[8];
    const float* bout = (const float*)d_in[9];

    const int N = N_NODES;
    const int E = N_EDGES;
    const int* srcv = ei;
    const int* dstv = ei + E;

    float* out  = (float*)d_out;            // [N]
    float* hout = (float*)d_out + N;        // [N x 64]

    char* ws = (char*)d_ws;
    int*   H       = (int*)ws;                          ws += sizeof(int) * NBUCK * GB;
    int*   bstart  = (int*)ws;                          ws += sizeof(int) * (NBUCK + 1);
    int*   rowoff  = (int*)ws;                          ws += sizeof(int) * (N + 1);
    int2*  P       = (int2*)ws;                         ws += sizeof(int2) * E;
    int*   csr_src = (int*)ws;                          ws += sizeof(int) * E;
    float* dis     = (float*)ws;                        ws += sizeof(float) * N;
    unsigned short* bufT = (unsigned short*)ws;         ws += sizeof(unsigned short) * (size_t)N * 128;
    float* bufH    = (float*)ws;                        // N*128 fp32

    // --- CSR build (two-level counting sort) ---
    hist_kernel<<<GB, 256, 0, stream>>>(dstv, H, E);
    scanH_kernel<<<1, 1024, 0, stream>>>(H, bstart, rowoff + N);
    partition_kernel<<<GB, 256, 0, stream>>>(srcv, dstv, H, P, E);
    bucket_csr_kernel<<<NBUCK, 256, 0, stream>>>(P, bstart, rowoff, dis, csr_src, N);

    const int aggBlocks = ((N + 1) / 2 * 64 + 255) / 256;  // 2 nodes per wave

    // --- layer 1: h1 = relu(agg(x@W1) + b1) ---
    gemm_kernel<128><<<dim3((N + 31) / 32, 2), 256, 0, stream>>>(x, W1, dis, bufT, N);
    aggregate128_kernel<<<aggBlocks, 256, 0, stream>>>(rowoff, csr_src, dis, bufT, b1, bufH, N);

    // --- layer 2: h2 = relu(agg(h1@Wh) + bh) ---
    gemm_kernel<128><<<dim3((N + 31) / 32, 2), 256, 0, stream>>>(bufH, Wh, dis, bufT, N);
    aggregate128_kernel<<<aggBlocks, 256, 0, stream>>>(rowoff, csr_src, dis, bufT, bh, bufH, N);

    // --- layer 3 + head: h3 = agg(h2@W2) + b2 ; out = h3@Wout + bout ---
    gemm_kernel<64><<<dim3((N + 31) / 32, 1), 256, 0, stream>>>(bufH, W2, dis, bufT, N);
    aggregate64_head_kernel<<<((size_t)N * 64 + 255) / 256, 256, 0, stream>>>(
        rowoff, csr_src, dis, bufT, b2, Wout, bout, hout, out, N);
}

// Round 7
// 327.234 us; speedup vs baseline: 10.9453x; 1.1618x over previous
//
#include <hip/hip_runtime.h>
#include <hip/hip_bf16.h>

// GCN: 3x GCNConv (sym-norm, self-loops) + linear head.
// N=50000 nodes, E=800000 edges, F: 128 -> 128 -> 128 -> 64 -> 1.
// Round 7: fix the self-inflicted scanH bottleneck (58 us: single block,
// uncoalesced stride-38 stripes, 0.14% occupancy). Hierarchical scan:
//   scan1 (196 blocks: per-bucket LDS scan of its 196 chunk counts -> local
//          exclusive offsets in H + bucket sum)
//   scan2 (1 block: scan of 196 bucket sums -> bstart)
//   partition cursors = bstart[bucket] + local offset.
// Everything else unchanged from round 6.

#define N_NODES 50000
#define N_EDGES 800000
#define NBUCK 196          // ceil(N/256) coarse buckets (dst>>8)
#define GB 196             // edge-chunk blocks
#define EPB 4096           // edges per block (GB*EPB >= E)

static __device__ __forceinline__ unsigned short f2bf(float f) {
    __hip_bfloat16 h = __float2bfloat16(f);  // RNE
    return *reinterpret_cast<unsigned short*>(&h);
}
static __device__ __forceinline__ float bf2f(unsigned short u) {
    return __uint_as_float(((unsigned)u) << 16);  // exact
}

// ---------- CSR build: two-level counting sort ----------

__global__ __launch_bounds__(256) void hist_kernel(const int* __restrict__ dstv,
                                                   int* __restrict__ H, int nE) {
    __shared__ int h[NBUCK];
    for (int i = threadIdx.x; i < NBUCK; i += 256) h[i] = 0;
    __syncthreads();
    int base = blockIdx.x * EPB;
#pragma unroll
    for (int i = 0; i < EPB / 256; ++i) {
        int e = base + i * 256 + threadIdx.x;
        if (e < nE) atomicAdd(&h[dstv[e] >> 8], 1);
    }
    __syncthreads();
    for (int i = threadIdx.x; i < NBUCK; i += 256)
        H[i * GB + blockIdx.x] = h[i];   // bucket-major
}

// Level 1: block k scans its bucket's GB chunk-counts -> local exclusive
// offsets (in place) + bucket total bsum[k].
__global__ __launch_bounds__(256) void scan1_kernel(int* __restrict__ H,
                                                    int* __restrict__ bsum) {
    __shared__ int s[256];
    int t = threadIdx.x;
    int k = blockIdx.x;
    int v = (t < GB) ? H[k * GB + t] : 0;
    s[t] = v;
    __syncthreads();
    for (int off = 1; off < 256; off <<= 1) {
        int u = (t >= off) ? s[t - off] : 0;
        __syncthreads();
        s[t] += u;
        __syncthreads();
    }
    if (t < GB) H[k * GB + t] = s[t] - v;  // local exclusive
    if (t == 255) bsum[k] = s[255];
}

// Level 2: scan the NBUCK bucket sums -> bstart.
__global__ __launch_bounds__(256) void scan2_kernel(const int* __restrict__ bsum,
                                                    int* __restrict__ bstart,
                                                    int* __restrict__ rowoff_last) {
    __shared__ int s[256];
    int t = threadIdx.x;
    int v = (t < NBUCK) ? bsum[t] : 0;
    s[t] = v;
    __syncthreads();
    for (int off = 1; off < 256; off <<= 1) {
        int u = (t >= off) ? s[t - off] : 0;
        __syncthreads();
        s[t] += u;
        __syncthreads();
    }
    if (t < NBUCK) bstart[t] = s[t] - v;  // exclusive
    if (t == 0) {
        bstart[NBUCK] = N_EDGES;
        *rowoff_last = N_EDGES;
    }
}

// Scatter (src,dst) pairs into bucket-partitioned P; per-(bucket,block) runs
// are contiguous so stores stay dense.
__global__ __launch_bounds__(256) void partition_kernel(const int* __restrict__ srcv,
                                                        const int* __restrict__ dstv,
                                                        const int* __restrict__ H,
                                                        const int* __restrict__ bstart,
                                                        int2* __restrict__ P, int nE) {
    __shared__ int cur[NBUCK];
    for (int i = threadIdx.x; i < NBUCK; i += 256)
        cur[i] = bstart[i] + H[i * GB + blockIdx.x];
    __syncthreads();
    int base = blockIdx.x * EPB;
#pragma unroll
    for (int i = 0; i < EPB / 256; ++i) {
        int e = base + i * 256 + threadIdx.x;
        if (e < nE) {
            int d = dstv[e];
            int sv = srcv[e];
            int pos = atomicAdd(&cur[d >> 8], 1);
            P[pos] = make_int2(sv, d);
        }
    }
}

// One block per bucket: 256 nodes, block-owned csr_src slice.
__global__ __launch_bounds__(256) void bucket_csr_kernel(const int2* __restrict__ P,
                                                         const int* __restrict__ bstart,
                                                         int* __restrict__ rowoff,
                                                         float* __restrict__ dis,
                                                         int* __restrict__ csr_src, int n) {
    __shared__ int cnt[256];
    __shared__ int s[256];
    __shared__ int cur[256];
    int t = threadIdx.x;
    int k = blockIdx.x;
    int ebeg = bstart[k], eend = bstart[k + 1];
    cnt[t] = 0;
    __syncthreads();
    for (int e = ebeg + t; e < eend; e += 256)
        atomicAdd(&cnt[P[e].y & 255], 1);
    __syncthreads();
    int myc = cnt[t];
    s[t] = myc;
    __syncthreads();
    for (int off = 1; off < 256; off <<= 1) {
        int v = (t >= off) ? s[t - off] : 0;
        __syncthreads();
        s[t] += v;
        __syncthreads();
    }
    int excl = s[t] - myc;
    int node = (k << 8) + t;
    if (node < n) {
        rowoff[node] = ebeg + excl;
        dis[node] = rsqrtf((float)(myc + 1));  // +1 self-loop
    }
    cur[t] = ebeg + excl;
    __syncthreads();
    for (int e = ebeg + t; e < eend; e += 256) {
        int2 p = P[e];
        int pos = atomicAdd(&cur[p.y & 255], 1);
        csr_src[pos] = p.x;
    }
}

// ---------- GEMM: C[r] = bf16((A[r] @ W) * scale[r]) ----------
// Col-split: block = 32 rows x 64 cols. LDS = 48 KB -> 3 blocks/CU.
template <int NOUT>
__global__ __launch_bounds__(256) void gemm_kernel(const float* __restrict__ A,
                                                   const float* __restrict__ W,
                                                   const float* __restrict__ scale,
                                                   unsigned short* __restrict__ C, int M) {
    __shared__ float sW[128 * 64];
    __shared__ float sA[32 * 128];

    int tid = threadIdx.x;
    int cg = tid & 15;
    int rg = tid >> 4;
    int row0 = blockIdx.x * 32;
    int col0 = blockIdx.y * 64;

    for (int i = tid; i < 128 * 16; i += 256) {
        int k = i >> 4;
        int c = i & 15;
        ((float4*)sW)[i] = *((const float4*)(W + (size_t)k * NOUT + col0) + c);
    }
    for (int i = tid; i < 32 * 32; i += 256) {
        int r = i >> 5;
        int c = i & 31;
        int gr = row0 + r;
        float4 v = make_float4(0.f, 0.f, 0.f, 0.f);
        if (gr < M) v = ((const float4*)(A + (size_t)gr * 128))[c];
        ((float4*)sA)[i] = v;
    }
    __syncthreads();

    float acc[2][4] = {};
#pragma unroll 4
    for (int k4 = 0; k4 < 32; ++k4) {
        float4 a0 = ((float4*)(sA + (rg * 2 + 0) * 128))[k4];
        float4 a1 = ((float4*)(sA + (rg * 2 + 1) * 128))[k4];
#pragma unroll
        for (int kk = 0; kk < 4; ++kk) {
            float4 w = ((float4*)sW)[(k4 * 4 + kk) * 16 + cg];
            float av0 = (kk == 0) ? a0.x : (kk == 1) ? a0.y : (kk == 2) ? a0.z : a0.w;
            float av1 = (kk == 0) ? a1.x : (kk == 1) ? a1.y : (kk == 2) ? a1.z : a1.w;
            acc[0][0] += av0 * w.x; acc[0][1] += av0 * w.y;
            acc[0][2] += av0 * w.z; acc[0][3] += av0 * w.w;
            acc[1][0] += av1 * w.x; acc[1][1] += av1 * w.y;
            acc[1][2] += av1 * w.z; acc[1][3] += av1 * w.w;
        }
    }
#pragma unroll
    for (int r = 0; r < 2; ++r) {
        int gr = row0 + rg * 2 + r;
        if (gr < M) {
            float sc = scale[gr];
            ushort4 o;
            o.x = f2bf(acc[r][0] * sc);
            o.y = f2bf(acc[r][1] * sc);
            o.z = f2bf(acc[r][2] * sc);
            o.w = f2bf(acc[r][3] * sc);
            *((ushort4*)(C + (size_t)gr * NOUT + col0) + cg) = o;
        }
    }
}

// ---------- Gather aggregation (bf16 rows): 2 nodes per wave ----------
__global__ __launch_bounds__(256) void aggregate128_kernel(
    const int* __restrict__ rowoff, const int* __restrict__ csr_src,
    const float* __restrict__ dis, const unsigned short* __restrict__ tp,
    const float* __restrict__ bias, float* __restrict__ hout, int n) {
    int wid = (blockIdx.x * 256 + threadIdx.x) >> 6;
    int lane = threadIdx.x & 63;
    int n0 = wid * 2;
    if (n0 >= n) return;
    int n1 = n0 + 1;
    bool has1 = (n1 < n);
    const ushort2* base = (const ushort2*)tp + lane;

    float dd0 = dis[n0];
    int beg0 = rowoff[n0];
    int mid  = rowoff[n0 + 1];
    int end1 = has1 ? rowoff[n1 + 1] : mid;
    float dd1 = has1 ? dis[n1] : 0.f;

    ushort2 s0 = base[(size_t)n0 * 64];
    float a0x = bf2f(s0.x), a0y = bf2f(s0.y);
    float a1x = 0.f, a1y = 0.f;
    if (has1) {
        ushort2 s1 = base[(size_t)n1 * 64];
        a1x = bf2f(s1.x);
        a1y = bf2f(s1.y);
    }

    int i0 = beg0, i1 = mid;
    while (i0 + 4 <= mid && i1 + 4 <= end1) {
        int p0 = csr_src[i0], p1 = csr_src[i0 + 1], p2 = csr_src[i0 + 2], p3 = csr_src[i0 + 3];
        int q0 = csr_src[i1], q1 = csr_src[i1 + 1], q2 = csr_src[i1 + 2], q3 = csr_src[i1 + 3];
        ushort2 u0 = base[(size_t)p0 * 64], u1 = base[(size_t)p1 * 64];
        ushort2 u2 = base[(size_t)p2 * 64], u3 = base[(size_t)p3 * 64];
        ushort2 v0 = base[(size_t)q0 * 64], v1 = base[(size_t)q1 * 64];
        ushort2 v2 = base[(size_t)q2 * 64], v3 = base[(size_t)q3 * 64];
        a0x += (bf2f(u0.x) + bf2f(u1.x)) + (bf2f(u2.x) + bf2f(u3.x));
        a0y += (bf2f(u0.y) + bf2f(u1.y)) + (bf2f(u2.y) + bf2f(u3.y));
        a1x += (bf2f(v0.x) + bf2f(v1.x)) + (bf2f(v2.x) + bf2f(v3.x));
        a1y += (bf2f(v0.y) + bf2f(v1.y)) + (bf2f(v2.y) + bf2f(v3.y));
        i0 += 4;
        i1 += 4;
    }
    for (; i0 + 4 <= mid; i0 += 4) {
        int p0 = csr_src[i0], p1 = csr_src[i0 + 1], p2 = csr_src[i0 + 2], p3 = csr_src[i0 + 3];
        ushort2 u0 = base[(size_t)p0 * 64], u1 = base[(size_t)p1 * 64];
        ushort2 u2 = base[(size_t)p2 * 64], u3 = base[(size_t)p3 * 64];
        a0x += (bf2f(u0.x) + bf2f(u1.x)) + (bf2f(u2.x) + bf2f(u3.x));
        a0y += (bf2f(u0.y) + bf2f(u1.y)) + (bf2f(u2.y) + bf2f(u3.y));
    }
    for (; i0 < mid; ++i0) {
        ushort2 u = base[(size_t)csr_src[i0] * 64];
        a0x += bf2f(u.x);
        a0y += bf2f(u.y);
    }
    for (; i1 + 4 <= end1; i1 += 4) {
        int q0 = csr_src[i1], q1 = csr_src[i1 + 1], q2 = csr_src[i1 + 2], q3 = csr_src[i1 + 3];
        ushort2 v0 = base[(size_t)q0 * 64], v1 = base[(size_t)q1 * 64];
        ushort2 v2 = base[(size_t)q2 * 64], v3 = base[(size_t)q3 * 64];
        a1x += (bf2f(v0.x) + bf2f(v1.x)) + (bf2f(v2.x) + bf2f(v3.x));
        a1y += (bf2f(v0.y) + bf2f(v1.y)) + (bf2f(v2.y) + bf2f(v3.y));
    }
    for (; i1 < end1; ++i1) {
        ushort2 v = base[(size_t)csr_src[i1] * 64];
        a1x += bf2f(v.x);
        a1y += bf2f(v.y);
    }

    float2 b = ((const float2*)bias)[lane];
    float r0x = fmaxf(a0x * dd0 + b.x, 0.f);
    float r0y = fmaxf(a0y * dd0 + b.y, 0.f);
    ((float2*)hout)[(size_t)n0 * 64 + lane] = make_float2(r0x, r0y);
    if (has1) {
        float r1x = fmaxf(a1x * dd1 + b.x, 0.f);
        float r1y = fmaxf(a1y * dd1 + b.y, 0.f);
        ((float2*)hout)[(size_t)n1 * 64 + lane] = make_float2(r1x, r1y);
    }
}

// F=64, no relu, fused head: h3 = dd*(tp[n]+sum tp[s]) + b2 ; out = h3@Wout + bout
__global__ __launch_bounds__(256) void aggregate64_head_kernel(
    const int* __restrict__ rowoff, const int* __restrict__ csr_src,
    const float* __restrict__ dis, const unsigned short* __restrict__ tp,
    const float* __restrict__ bias, const float* __restrict__ Wout,
    const float* __restrict__ bout, float* __restrict__ hout,
    float* __restrict__ out, int n) {
    int node = (blockIdx.x * 256 + threadIdx.x) >> 6;
    int lane = threadIdx.x & 63;
    if (node >= n) return;
    float dd = dis[node];
    const unsigned short* base = tp + lane;
    float acc = bf2f(base[(size_t)node * 64]);
    int beg = rowoff[node], end = rowoff[node + 1];
    int i = beg;
    for (; i + 4 <= end; i += 4) {
        int s0 = csr_src[i], s1 = csr_src[i + 1], s2 = csr_src[i + 2], s3 = csr_src[i + 3];
        float v0 = bf2f(base[(size_t)s0 * 64]);
        float v1 = bf2f(base[(size_t)s1 * 64]);
        float v2 = bf2f(base[(size_t)s2 * 64]);
        float v3 = bf2f(base[(size_t)s3 * 64]);
        acc += (v0 + v1) + (v2 + v3);
    }
    for (; i < end; ++i) acc += bf2f(base[(size_t)csr_src[i] * 64]);
    acc = acc * dd + bias[lane];
    hout[(size_t)node * 64 + lane] = acc;
    float p = acc * Wout[lane];
#pragma unroll
    for (int off = 32; off > 0; off >>= 1) p += __shfl_down(p, off);
    if (lane == 0) out[node] = p + bout[0];
}

extern "C" void kernel_launch(void* const* d_in, const int* in_sizes, int n_in,
                              void* d_out, int out_size, void* d_ws, size_t ws_size,
                              hipStream_t stream) {
    const float* x    = (const float*)d_in[0];
    const int*   ei   = (const int*)d_in[1];  // [2, E] flat: src then dst
    const float* W1   = (const float*)d_in[2];
    const float* b1   = (const float*)d_in[3];
    const float* Wh   = (const float*)d_in[4];
    const float* bh   = (const float*)d_in[5];
    const float* W2   = (const float*)d_in[6];
    const float* b2   = (const float*)d_in[7];
    const float* Wout = (const float*)d_in[8];
    const float* bout = (const float*)d_in[9];

    const int N = N_NODES;
    const int E = N_EDGES;
    const int* srcv = ei;
    const int* dstv = ei + E;

    float* out  = (float*)d_out;            // [N]
    float* hout = (float*)d_out + N;        // [N x 64]

    char* ws = (char*)d_ws;
    int*   H       = (int*)ws;                          ws += sizeof(int) * NBUCK * GB;
    int*   bsum    = (int*)ws;                          ws += sizeof(int) * NBUCK;
    int*   bstart  = (int*)ws;                          ws += sizeof(int) * (NBUCK + 1);
    int*   rowoff  = (int*)ws;                          ws += sizeof(int) * (N + 1);
    int2*  P       = (int2*)ws;                         ws += sizeof(int2) * E;
    int*   csr_src = (int*)ws;                          ws += sizeof(int) * E;
    float* dis     = (float*)ws;                        ws += sizeof(float) * N;
    unsigned short* bufT = (unsigned short*)ws;         ws += sizeof(unsigned short) * (size_t)N * 128;
    float* bufH    = (float*)ws;                        // N*128 fp32

    // --- CSR build (two-level counting sort, hierarchical scan) ---
    hist_kernel<<<GB, 256, 0, stream>>>(dstv, H, E);
    scan1_kernel<<<NBUCK, 256, 0, stream>>>(H, bsum);
    scan2_kernel<<<1, 256, 0, stream>>>(bsum, bstart, rowoff + N);
    partition_kernel<<<GB, 256, 0, stream>>>(srcv, dstv, H, bstart, P, E);
    bucket_csr_kernel<<<NBUCK, 256, 0, stream>>>(P, bstart, rowoff, dis, csr_src, N);

    const int aggBlocks = ((N + 1) / 2 * 64 + 255) / 256;  // 2 nodes per wave

    // --- layer 1: h1 = relu(agg(x@W1) + b1) ---
    gemm_kernel<128><<<dim3((N + 31) / 32, 2), 256, 0, stream>>>(x, W1, dis, bufT, N);
    aggregate128_kernel<<<aggBlocks, 256, 0, stream>>>(rowoff, csr_src, dis, bufT, b1, bufH, N);

    // --- layer 2: h2 = relu(agg(h1@Wh) + bh) ---
    gemm_kernel<128><<<dim3((N + 31) / 32, 2), 256, 0, stream>>>(bufH, Wh, dis, bufT, N);
    aggregate128_kernel<<<aggBlocks, 256, 0, stream>>>(rowoff, csr_src, dis, bufT, bh, bufH, N);

    // --- layer 3 + head: h3 = agg(h2@W2) + b2 ; out = h3@Wout + bout ---
    gemm_kernel<64><<<dim3((N + 31) / 32, 1), 256, 0, stream>>>(bufH, W2, dis, bufT, N);
    aggregate64_head_kernel<<<((size_t)N * 64 + 255) / 256, 256, 0, stream>>>(
        rowoff, csr_src, dis, bufT, b2, Wout, bout, hout, out, N);
}

// Round 8
// 310.253 us; speedup vs baseline: 11.5444x; 1.0547x over previous
//
#include <hip/hip_runtime.h>
#include <hip/hip_bf16.h>

// GCN: 3x GCNConv (sym-norm, self-loops) + linear head.
// N=50000 nodes, E=800000 edges, F: 128 -> 128 -> 128 -> 64 -> 1.
// Round 8: GEMM -> MFMA (matrix pipe was idle; vector gemm was LDS-issue
// bound at 37 TF with 3.2M bank conflicts). fp32 accuracy preserved via
// split-bf16: a = hi + lo, A*B ~= Ah*Bh + Ah*Bl + Al*Bh (residual ~2^-17).
//   wprep: W -> transposed bf16 hi/lo [col][k] (B-frag wants K-contiguous)
//   gemm_mfma: 64x64 tile, 4 waves x 2x2 16x16 C-frags, whole K=128 in LDS
//              (stride 136 bf16: 16 B aligned frags, 2-way-only banks on
//              staging, 68 KB -> 2 blocks/CU), 4 ksteps x 12 mfma_16x16x32.
// CSR build + aggregates unchanged from round 7.

#define N_NODES 50000
#define N_EDGES 800000
#define NBUCK 196          // ceil(N/256) coarse buckets (dst>>8)
#define GB 196             // edge-chunk blocks
#define EPB 4096           // edges per block (GB*EPB >= E)

typedef __attribute__((ext_vector_type(8))) short short8;   // 8 bf16 = 4 VGPR
typedef __attribute__((ext_vector_type(4))) float f32x4;    // MFMA C/D

static __device__ __forceinline__ unsigned short f2bf(float f) {
    __hip_bfloat16 h = __float2bfloat16(f);  // RNE
    return *reinterpret_cast<unsigned short*>(&h);
}
static __device__ __forceinline__ float bf2f(unsigned short u) {
    return __uint_as_float(((unsigned)u) << 16);  // exact
}

// ---------- CSR build: two-level counting sort ----------

__global__ __launch_bounds__(256) void hist_kernel(const int* __restrict__ dstv,
                                                   int* __restrict__ H, int nE) {
    __shared__ int h[NBUCK];
    for (int i = threadIdx.x; i < NBUCK; i += 256) h[i] = 0;
    __syncthreads();
    int base = blockIdx.x * EPB;
#pragma unroll
    for (int i = 0; i < EPB / 256; ++i) {
        int e = base + i * 256 + threadIdx.x;
        if (e < nE) atomicAdd(&h[dstv[e] >> 8], 1);
    }
    __syncthreads();
    for (int i = threadIdx.x; i < NBUCK; i += 256)
        H[i * GB + blockIdx.x] = h[i];   // bucket-major
}

__global__ __launch_bounds__(256) void scan1_kernel(int* __restrict__ H,
                                                    int* __restrict__ bsum) {
    __shared__ int s[256];
    int t = threadIdx.x;
    int k = blockIdx.x;
    int v = (t < GB) ? H[k * GB + t] : 0;
    s[t] = v;
    __syncthreads();
    for (int off = 1; off < 256; off <<= 1) {
        int u = (t >= off) ? s[t - off] : 0;
        __syncthreads();
        s[t] += u;
        __syncthreads();
    }
    if (t < GB) H[k * GB + t] = s[t] - v;  // local exclusive
    if (t == 255) bsum[k] = s[255];
}

__global__ __launch_bounds__(256) void scan2_kernel(const int* __restrict__ bsum,
                                                    int* __restrict__ bstart,
                                                    int* __restrict__ rowoff_last) {
    __shared__ int s[256];
    int t = threadIdx.x;
    int v = (t < NBUCK) ? bsum[t] : 0;
    s[t] = v;
    __syncthreads();
    for (int off = 1; off < 256; off <<= 1) {
        int u = (t >= off) ? s[t - off] : 0;
        __syncthreads();
        s[t] += u;
        __syncthreads();
    }
    if (t < NBUCK) bstart[t] = s[t] - v;  // exclusive
    if (t == 0) {
        bstart[NBUCK] = N_EDGES;
        *rowoff_last = N_EDGES;
    }
}

__global__ __launch_bounds__(256) void partition_kernel(const int* __restrict__ srcv,
                                                        const int* __restrict__ dstv,
                                                        const int* __restrict__ H,
                                                        const int* __restrict__ bstart,
                                                        int2* __restrict__ P, int nE) {
    __shared__ int cur[NBUCK];
    for (int i = threadIdx.x; i < NBUCK; i += 256)
        cur[i] = bstart[i] + H[i * GB + blockIdx.x];
    __syncthreads();
    int base = blockIdx.x * EPB;
#pragma unroll
    for (int i = 0; i < EPB / 256; ++i) {
        int e = base + i * 256 + threadIdx.x;
        if (e < nE) {
            int d = dstv[e];
            int sv = srcv[e];
            int pos = atomicAdd(&cur[d >> 8], 1);
            P[pos] = make_int2(sv, d);
        }
    }
}

__global__ __launch_bounds__(256) void bucket_csr_kernel(const int2* __restrict__ P,
                                                         const int* __restrict__ bstart,
                                                         int* __restrict__ rowoff,
                                                         float* __restrict__ dis,
                                                         int* __restrict__ csr_src, int n) {
    __shared__ int cnt[256];
    __shared__ int s[256];
    __shared__ int cur[256];
    int t = threadIdx.x;
    int k = blockIdx.x;
    int ebeg = bstart[k], eend = bstart[k + 1];
    cnt[t] = 0;
    __syncthreads();
    for (int e = ebeg + t; e < eend; e += 256)
        atomicAdd(&cnt[P[e].y & 255], 1);
    __syncthreads();
    int myc = cnt[t];
    s[t] = myc;
    __syncthreads();
    for (int off = 1; off < 256; off <<= 1) {
        int v = (t >= off) ? s[t - off] : 0;
        __syncthreads();
        s[t] += v;
        __syncthreads();
    }
    int excl = s[t] - myc;
    int node = (k << 8) + t;
    if (node < n) {
        rowoff[node] = ebeg + excl;
        dis[node] = rsqrtf((float)(myc + 1));  // +1 self-loop
    }
    cur[t] = ebeg + excl;
    __syncthreads();
    for (int e = ebeg + t; e < eend; e += 256) {
        int2 p = P[e];
        int pos = atomicAdd(&cur[p.y & 255], 1);
        csr_src[pos] = p.x;
    }
}

// ---------- W prep: W[k][col] fp32 -> Wt hi/lo bf16 [col][k] ----------
__global__ __launch_bounds__(256) void wprep_kernel(const float* __restrict__ W,
                                                    unsigned short* __restrict__ Whi,
                                                    unsigned short* __restrict__ Wlo,
                                                    int nout) {
    int t = blockIdx.x * 256 + threadIdx.x;
    if (t >= nout * 128) return;
    int col = t >> 7, k = t & 127;
    float v = W[(size_t)k * nout + col];
    unsigned short hi = f2bf(v);
    unsigned short lo = f2bf(v - bf2f(hi));
    Whi[(size_t)col * 128 + k] = hi;   // k-contiguous (coalesced writes)
    Wlo[(size_t)col * 128 + k] = lo;
}

// ---------- MFMA GEMM: C[r] = bf16((A[r] @ W) * scale[r]) ----------
// Block = 64 rows x 64 cols, 4 waves, split-bf16 x3 passes, whole K in LDS.
template <int NOUT>
__global__ __launch_bounds__(256) void gemm_mfma_kernel(
    const float* __restrict__ A,
    const unsigned short* __restrict__ Wthi,  // [NOUT][128] bf16
    const unsigned short* __restrict__ Wtlo,
    const float* __restrict__ scale,
    unsigned short* __restrict__ C, int M) {
    constexpr int LDK = 136;  // bf16 stride: 16 B-aligned frags, bank spread
    __shared__ unsigned short sAhi[64 * LDK];
    __shared__ unsigned short sAlo[64 * LDK];
    __shared__ unsigned short sBhi[64 * LDK];
    __shared__ unsigned short sBlo[64 * LDK];

    int tid = threadIdx.x;
    int Rbase = blockIdx.x * 64;
    int Cbase = blockIdx.y * 64;

    // stage A: 64 rows x 128 fp32 -> hi/lo bf16
    for (int i = tid; i < 64 * 32; i += 256) {
        int r = i >> 5, c4 = i & 31;
        int row = Rbase + r;
        float4 v = make_float4(0.f, 0.f, 0.f, 0.f);
        if (row < M) v = ((const float4*)(A + (size_t)row * 128))[c4];
        ushort4 hi, lo;
        hi.x = f2bf(v.x); lo.x = f2bf(v.x - bf2f(hi.x));
        hi.y = f2bf(v.y); lo.y = f2bf(v.y - bf2f(hi.y));
        hi.z = f2bf(v.z); lo.z = f2bf(v.z - bf2f(hi.z));
        hi.w = f2bf(v.w); lo.w = f2bf(v.w - bf2f(hi.w));
        *(ushort4*)(sAhi + r * LDK + c4 * 4) = hi;
        *(ushort4*)(sAlo + r * LDK + c4 * 4) = lo;
    }
    // stage B: Wt slab, 64 cols x 128 k bf16 (already hi/lo in global)
    for (int i = tid; i < 64 * 32; i += 256) {
        int c = i >> 5, k4 = i & 31;
        *(ushort4*)(sBhi + c * LDK + k4 * 4) =
            *((const ushort4*)(Wthi + (size_t)(Cbase + c) * 128) + k4);
        *(ushort4*)(sBlo + c * LDK + k4 * 4) =
            *((const ushort4*)(Wtlo + (size_t)(Cbase + c) * 128) + k4);
    }
    __syncthreads();

    int w = tid >> 6, lane = tid & 63;
    int quad = lane >> 4, m = lane & 15;
    int r0 = (w & 1) * 32, c0 = (w >> 1) * 32;

    f32x4 z = {0.f, 0.f, 0.f, 0.f};
    f32x4 acc00 = z, acc01 = z, acc10 = z, acc11 = z;

#pragma unroll
    for (int ks = 0; ks < 4; ++ks) {
        int kof = ks * 32 + quad * 8;
        short8 ah0 = *(const short8*)(sAhi + (r0 + m) * LDK + kof);
        short8 ah1 = *(const short8*)(sAhi + (r0 + 16 + m) * LDK + kof);
        short8 al0 = *(const short8*)(sAlo + (r0 + m) * LDK + kof);
        short8 al1 = *(const short8*)(sAlo + (r0 + 16 + m) * LDK + kof);
        short8 bh0 = *(const short8*)(sBhi + (c0 + m) * LDK + kof);
        short8 bh1 = *(const short8*)(sBhi + (c0 + 16 + m) * LDK + kof);
        short8 bl0 = *(const short8*)(sBlo + (c0 + m) * LDK + kof);
        short8 bl1 = *(const short8*)(sBlo + (c0 + 16 + m) * LDK + kof);
        // hi*hi + hi*lo + lo*hi (lo*lo dropped, ~2^-18)
        acc00 = __builtin_amdgcn_mfma_f32_16x16x32_bf16(ah0, bh0, acc00, 0, 0, 0);
        acc01 = __builtin_amdgcn_mfma_f32_16x16x32_bf16(ah0, bh1, acc01, 0, 0, 0);
        acc10 = __builtin_amdgcn_mfma_f32_16x16x32_bf16(ah1, bh0, acc10, 0, 0, 0);
        acc11 = __builtin_amdgcn_mfma_f32_16x16x32_bf16(ah1, bh1, acc11, 0, 0, 0);
        acc00 = __builtin_amdgcn_mfma_f32_16x16x32_bf16(ah0, bl0, acc00, 0, 0, 0);
        acc01 = __builtin_amdgcn_mfma_f32_16x16x32_bf16(ah0, bl1, acc01, 0, 0, 0);
        acc10 = __builtin_amdgcn_mfma_f32_16x16x32_bf16(ah1, bl0, acc10, 0, 0, 0);
        acc11 = __builtin_amdgcn_mfma_f32_16x16x32_bf16(ah1, bl1, acc11, 0, 0, 0);
        acc00 = __builtin_amdgcn_mfma_f32_16x16x32_bf16(al0, bh0, acc00, 0, 0, 0);
        acc01 = __builtin_amdgcn_mfma_f32_16x16x32_bf16(al0, bh1, acc01, 0, 0, 0);
        acc10 = __builtin_amdgcn_mfma_f32_16x16x32_bf16(al1, bh0, acc10, 0, 0, 0);
        acc11 = __builtin_amdgcn_mfma_f32_16x16x32_bf16(al1, bh1, acc11, 0, 0, 0);
    }

    // epilogue: C/D layout col = lane&15, row = quad*4 + reg
#pragma unroll
    for (int reg = 0; reg < 4; ++reg) {
        int row0g = Rbase + r0 + quad * 4 + reg;
        if (row0g < M) {
            float sc = scale[row0g];
            C[(size_t)row0g * NOUT + Cbase + c0 + m]      = f2bf(acc00[reg] * sc);
            C[(size_t)row0g * NOUT + Cbase + c0 + 16 + m] = f2bf(acc01[reg] * sc);
        }
        int row1g = row0g + 16;
        if (row1g < M) {
            float sc = scale[row1g];
            C[(size_t)row1g * NOUT + Cbase + c0 + m]      = f2bf(acc10[reg] * sc);
            C[(size_t)row1g * NOUT + Cbase + c0 + 16 + m] = f2bf(acc11[reg] * sc);
        }
    }
}

// ---------- Gather aggregation (bf16 rows): 2 nodes per wave ----------
__global__ __launch_bounds__(256) void aggregate128_kernel(
    const int* __restrict__ rowoff, const int* __restrict__ csr_src,
    const float* __restrict__ dis, const unsigned short* __restrict__ tp,
    const float* __restrict__ bias, float* __restrict__ hout, int n) {
    int wid = (blockIdx.x * 256 + threadIdx.x) >> 6;
    int lane = threadIdx.x & 63;
    int n0 = wid * 2;
    if (n0 >= n) return;
    int n1 = n0 + 1;
    bool has1 = (n1 < n);
    const ushort2* base = (const ushort2*)tp + lane;

    float dd0 = dis[n0];
    int beg0 = rowoff[n0];
    int mid  = rowoff[n0 + 1];
    int end1 = has1 ? rowoff[n1 + 1] : mid;
    float dd1 = has1 ? dis[n1] : 0.f;

    ushort2 s0 = base[(size_t)n0 * 64];
    float a0x = bf2f(s0.x), a0y = bf2f(s0.y);
    float a1x = 0.f, a1y = 0.f;
    if (has1) {
        ushort2 s1 = base[(size_t)n1 * 64];
        a1x = bf2f(s1.x);
        a1y = bf2f(s1.y);
    }

    int i0 = beg0, i1 = mid;
    while (i0 + 4 <= mid && i1 + 4 <= end1) {
        int p0 = csr_src[i0], p1 = csr_src[i0 + 1], p2 = csr_src[i0 + 2], p3 = csr_src[i0 + 3];
        int q0 = csr_src[i1], q1 = csr_src[i1 + 1], q2 = csr_src[i1 + 2], q3 = csr_src[i1 + 3];
        ushort2 u0 = base[(size_t)p0 * 64], u1 = base[(size_t)p1 * 64];
        ushort2 u2 = base[(size_t)p2 * 64], u3 = base[(size_t)p3 * 64];
        ushort2 v0 = base[(size_t)q0 * 64], v1 = base[(size_t)q1 * 64];
        ushort2 v2 = base[(size_t)q2 * 64], v3 = base[(size_t)q3 * 64];
        a0x += (bf2f(u0.x) + bf2f(u1.x)) + (bf2f(u2.x) + bf2f(u3.x));
        a0y += (bf2f(u0.y) + bf2f(u1.y)) + (bf2f(u2.y) + bf2f(u3.y));
        a1x += (bf2f(v0.x) + bf2f(v1.x)) + (bf2f(v2.x) + bf2f(v3.x));
        a1y += (bf2f(v0.y) + bf2f(v1.y)) + (bf2f(v2.y) + bf2f(v3.y));
        i0 += 4;
        i1 += 4;
    }
    for (; i0 + 4 <= mid; i0 += 4) {
        int p0 = csr_src[i0], p1 = csr_src[i0 + 1], p2 = csr_src[i0 + 2], p3 = csr_src[i0 + 3];
        ushort2 u0 = base[(size_t)p0 * 64], u1 = base[(size_t)p1 * 64];
        ushort2 u2 = base[(size_t)p2 * 64], u3 = base[(size_t)p3 * 64];
        a0x += (bf2f(u0.x) + bf2f(u1.x)) + (bf2f(u2.x) + bf2f(u3.x));
        a0y += (bf2f(u0.y) + bf2f(u1.y)) + (bf2f(u2.y) + bf2f(u3.y));
    }
    for (; i0 < mid; ++i0) {
        ushort2 u = base[(size_t)csr_src[i0] * 64];
        a0x += bf2f(u.x);
        a0y += bf2f(u.y);
    }
    for (; i1 + 4 <= end1; i1 += 4) {
        int q0 = csr_src[i1], q1 = csr_src[i1 + 1], q2 = csr_src[i1 + 2], q3 = csr_src[i1 + 3];
        ushort2 v0 = base[(size_t)q0 * 64], v1 = base[(size_t)q1 * 64];
        ushort2 v2 = base[(size_t)q2 * 64], v3 = base[(size_t)q3 * 64];
        a1x += (bf2f(v0.x) + bf2f(v1.x)) + (bf2f(v2.x) + bf2f(v3.x));
        a1y += (bf2f(v0.y) + bf2f(v1.y)) + (bf2f(v2.y) + bf2f(v3.y));
    }
    for (; i1 < end1; ++i1) {
        ushort2 v = base[(size_t)csr_src[i1] * 64];
        a1x += bf2f(v.x);
        a1y += bf2f(v.y);
    }

    float2 b = ((const float2*)bias)[lane];
    float r0x = fmaxf(a0x * dd0 + b.x, 0.f);
    float r0y = fmaxf(a0y * dd0 + b.y, 0.f);
    ((float2*)hout)[(size_t)n0 * 64 + lane] = make_float2(r0x, r0y);
    if (has1) {
        float r1x = fmaxf(a1x * dd1 + b.x, 0.f);
        float r1y = fmaxf(a1y * dd1 + b.y, 0.f);
        ((float2*)hout)[(size_t)n1 * 64 + lane] = make_float2(r1x, r1y);
    }
}

// F=64, no relu, fused head: h3 = dd*(tp[n]+sum tp[s]) + b2 ; out = h3@Wout + bout
__global__ __launch_bounds__(256) void aggregate64_head_kernel(
    const int* __restrict__ rowoff, const int* __restrict__ csr_src,
    const float* __restrict__ dis, const unsigned short* __restrict__ tp,
    const float* __restrict__ bias, const float* __restrict__ Wout,
    const float* __restrict__ bout, float* __restrict__ hout,
    float* __restrict__ out, int n) {
    int node = (blockIdx.x * 256 + threadIdx.x) >> 6;
    int lane = threadIdx.x & 63;
    if (node >= n) return;
    float dd = dis[node];
    const unsigned short* base = tp + lane;
    float acc = bf2f(base[(size_t)node * 64]);
    int beg = rowoff[node], end = rowoff[node + 1];
    int i = beg;
    for (; i + 4 <= end; i += 4) {
        int s0 = csr_src[i], s1 = csr_src[i + 1], s2 = csr_src[i + 2], s3 = csr_src[i + 3];
        float v0 = bf2f(base[(size_t)s0 * 64]);
        float v1 = bf2f(base[(size_t)s1 * 64]);
        float v2 = bf2f(base[(size_t)s2 * 64]);
        float v3 = bf2f(base[(size_t)s3 * 64]);
        acc += (v0 + v1) + (v2 + v3);
    }
    for (; i < end; ++i) acc += bf2f(base[(size_t)csr_src[i] * 64]);
    acc = acc * dd + bias[lane];
    hout[(size_t)node * 64 + lane] = acc;
    float p = acc * Wout[lane];
#pragma unroll
    for (int off = 32; off > 0; off >>= 1) p += __shfl_down(p, off);
    if (lane == 0) out[node] = p + bout[0];
}

extern "C" void kernel_launch(void* const* d_in, const int* in_sizes, int n_in,
                              void* d_out, int out_size, void* d_ws, size_t ws_size,
                              hipStream_t stream) {
    const float* x    = (const float*)d_in[0];
    const int*   ei   = (const int*)d_in[1];  // [2, E] flat: src then dst
    const float* W1   = (const float*)d_in[2];
    const float* b1   = (const float*)d_in[3];
    const float* Wh   = (const float*)d_in[4];
    const float* bh   = (const float*)d_in[5];
    const float* W2   = (const float*)d_in[6];
    const float* b2   = (const float*)d_in[7];
    const float* Wout = (const float*)d_in[8];
    const float* bout = (const float*)d_in[9];

    const int N = N_NODES;
    const int E = N_EDGES;
    const int* srcv = ei;
    const int* dstv = ei + E;

    float* out  = (float*)d_out;            // [N]
    float* hout = (float*)d_out + N;        // [N x 64]

    char* ws = (char*)d_ws;
    int*   H       = (int*)ws;                          ws += sizeof(int) * NBUCK * GB;
    int*   bsum    = (int*)ws;                          ws += sizeof(int) * NBUCK;
    int*   bstart  = (int*)ws;                          ws += sizeof(int) * (NBUCK + 1);
    int*   rowoff  = (int*)ws;                          ws += sizeof(int) * (N + 1);
    int2*  P       = (int2*)ws;                         ws += sizeof(int2) * E;
    int*   csr_src = (int*)ws;                          ws += sizeof(int) * E;
    float* dis     = (float*)ws;                        ws += sizeof(float) * N;
    unsigned short* W1thi = (unsigned short*)ws;        ws += sizeof(unsigned short) * 128 * 128;
    unsigned short* W1tlo = (unsigned short*)ws;        ws += sizeof(unsigned short) * 128 * 128;
    unsigned short* Whthi = (unsigned short*)ws;        ws += sizeof(unsigned short) * 128 * 128;
    unsigned short* Whtlo = (unsigned short*)ws;        ws += sizeof(unsigned short) * 128 * 128;
    unsigned short* W2thi = (unsigned short*)ws;        ws += sizeof(unsigned short) * 64 * 128;
    unsigned short* W2tlo = (unsigned short*)ws;        ws += sizeof(unsigned short) * 64 * 128;
    unsigned short* bufT  = (unsigned short*)ws;        ws += sizeof(unsigned short) * (size_t)N * 128;
    float* bufH    = (float*)ws;                        // N*128 fp32

    // --- W prep (bf16 hi/lo transposed) ---
    wprep_kernel<<<(128 * 128 + 255) / 256, 256, 0, stream>>>(W1, W1thi, W1tlo, 128);
    wprep_kernel<<<(128 * 128 + 255) / 256, 256, 0, stream>>>(Wh, Whthi, Whtlo, 128);
    wprep_kernel<<<(64 * 128 + 255) / 256, 256, 0, stream>>>(W2, W2thi, W2tlo, 64);

    // --- CSR build (two-level counting sort, hierarchical scan) ---
    hist_kernel<<<GB, 256, 0, stream>>>(dstv, H, E);
    scan1_kernel<<<NBUCK, 256, 0, stream>>>(H, bsum);
    scan2_kernel<<<1, 256, 0, stream>>>(bsum, bstart, rowoff + N);
    partition_kernel<<<GB, 256, 0, stream>>>(srcv, dstv, H, bstart, P, E);
    bucket_csr_kernel<<<NBUCK, 256, 0, stream>>>(P, bstart, rowoff, dis, csr_src, N);

    const int aggBlocks = ((N + 1) / 2 * 64 + 255) / 256;  // 2 nodes per wave
    const int gemmRows = (N + 63) / 64;                    // 782

    // --- layer 1: h1 = relu(agg(x@W1) + b1) ---
    gemm_mfma_kernel<128><<<dim3(gemmRows, 2), 256, 0, stream>>>(x, W1thi, W1tlo, dis, bufT, N);
    aggregate128_kernel<<<aggBlocks, 256, 0, stream>>>(rowoff, csr_src, dis, bufT, b1, bufH, N);

    // --- layer 2: h2 = relu(agg(h1@Wh) + bh) ---
    gemm_mfma_kernel<128><<<dim3(gemmRows, 2), 256, 0, stream>>>(bufH, Whthi, Whtlo, dis, bufT, N);
    aggregate128_kernel<<<aggBlocks, 256, 0, stream>>>(rowoff, csr_src, dis, bufT, bh, bufH, N);

    // --- layer 3 + head: h3 = agg(h2@W2) + b2 ; out = h3@Wout + bout ---
    gemm_mfma_kernel<64><<<dim3(gemmRows, 1), 256, 0, stream>>>(bufH, W2thi, W2tlo, dis, bufT, N);
    aggregate64_head_kernel<<<((size_t)N * 64 + 255) / 256, 256, 0, stream>>>(
        rowoff, csr_src, dis, bufT, b2, Wout, bout, hout, out, N);
}

// Round 9
// 303.228 us; speedup vs baseline: 11.8118x; 1.0232x over previous
//
#include <hip/hip_runtime.h>
#include <hip/hip_bf16.h>

// GCN: 3x GCNConv (sym-norm, self-loops) + linear head.
// N=50000 nodes, E=800000 edges, F: 128 -> 128 -> 128 -> 64 -> 1.
// Round 9:
//  - gemm_mfma v2: B (weights) in registers (loaded once per wave from the
//    k-contiguous Wt), LDS holds A hi/lo only (34 KB -> 3-4 blocks/CU vs 2).
//    Round-8's 68 KB LDS + one-shot staging left global latency exposed.
//  - aggregate v2: half-wave row gather (32 lanes x ushort4 = one 256 B row
//    per half-wave) -> 2 edge-rows per load instr, even/odd edges split
//    across halves, combined with shfl_xor(32). 2 nodes/wave + unroll-2
//    joint phase = up to 8 rows in flight per wave.
//  - wprep fused to one launch.
// CSR build unchanged from round 7.

#define N_NODES 50000
#define N_EDGES 800000
#define NBUCK 196          // ceil(N/256) coarse buckets (dst>>8)
#define GB 196             // edge-chunk blocks
#define EPB 4096           // edges per block (GB*EPB >= E)

typedef __attribute__((ext_vector_type(8))) short short8;   // 8 bf16 = 4 VGPR
typedef __attribute__((ext_vector_type(4))) float f32x4;    // MFMA C/D

static __device__ __forceinline__ unsigned short f2bf(float f) {
    __hip_bfloat16 h = __float2bfloat16(f);  // RNE
    return *reinterpret_cast<unsigned short*>(&h);
}
static __device__ __forceinline__ float bf2f(unsigned short u) {
    return __uint_as_float(((unsigned)u) << 16);  // exact
}

// ---------- CSR build: two-level counting sort ----------

__global__ __launch_bounds__(256) void hist_kernel(const int* __restrict__ dstv,
                                                   int* __restrict__ H, int nE) {
    __shared__ int h[NBUCK];
    for (int i = threadIdx.x; i < NBUCK; i += 256) h[i] = 0;
    __syncthreads();
    int base = blockIdx.x * EPB;
#pragma unroll
    for (int i = 0; i < EPB / 256; ++i) {
        int e = base + i * 256 + threadIdx.x;
        if (e < nE) atomicAdd(&h[dstv[e] >> 8], 1);
    }
    __syncthreads();
    for (int i = threadIdx.x; i < NBUCK; i += 256)
        H[i * GB + blockIdx.x] = h[i];   // bucket-major
}

__global__ __launch_bounds__(256) void scan1_kernel(int* __restrict__ H,
                                                    int* __restrict__ bsum) {
    __shared__ int s[256];
    int t = threadIdx.x;
    int k = blockIdx.x;
    int v = (t < GB) ? H[k * GB + t] : 0;
    s[t] = v;
    __syncthreads();
    for (int off = 1; off < 256; off <<= 1) {
        int u = (t >= off) ? s[t - off] : 0;
        __syncthreads();
        s[t] += u;
        __syncthreads();
    }
    if (t < GB) H[k * GB + t] = s[t] - v;  // local exclusive
    if (t == 255) bsum[k] = s[255];
}

__global__ __launch_bounds__(256) void scan2_kernel(const int* __restrict__ bsum,
                                                    int* __restrict__ bstart,
                                                    int* __restrict__ rowoff_last) {
    __shared__ int s[256];
    int t = threadIdx.x;
    int v = (t < NBUCK) ? bsum[t] : 0;
    s[t] = v;
    __syncthreads();
    for (int off = 1; off < 256; off <<= 1) {
        int u = (t >= off) ? s[t - off] : 0;
        __syncthreads();
        s[t] += u;
        __syncthreads();
    }
    if (t < NBUCK) bstart[t] = s[t] - v;  // exclusive
    if (t == 0) {
        bstart[NBUCK] = N_EDGES;
        *rowoff_last = N_EDGES;
    }
}

__global__ __launch_bounds__(256) void partition_kernel(const int* __restrict__ srcv,
                                                        const int* __restrict__ dstv,
                                                        const int* __restrict__ H,
                                                        const int* __restrict__ bstart,
                                                        int2* __restrict__ P, int nE) {
    __shared__ int cur[NBUCK];
    for (int i = threadIdx.x; i < NBUCK; i += 256)
        cur[i] = bstart[i] + H[i * GB + blockIdx.x];
    __syncthreads();
    int base = blockIdx.x * EPB;
#pragma unroll
    for (int i = 0; i < EPB / 256; ++i) {
        int e = base + i * 256 + threadIdx.x;
        if (e < nE) {
            int d = dstv[e];
            int sv = srcv[e];
            int pos = atomicAdd(&cur[d >> 8], 1);
            P[pos] = make_int2(sv, d);
        }
    }
}

__global__ __launch_bounds__(256) void bucket_csr_kernel(const int2* __restrict__ P,
                                                         const int* __restrict__ bstart,
                                                         int* __restrict__ rowoff,
                                                         float* __restrict__ dis,
                                                         int* __restrict__ csr_src, int n) {
    __shared__ int cnt[256];
    __shared__ int s[256];
    __shared__ int cur[256];
    int t = threadIdx.x;
    int k = blockIdx.x;
    int ebeg = bstart[k], eend = bstart[k + 1];
    cnt[t] = 0;
    __syncthreads();
    for (int e = ebeg + t; e < eend; e += 256)
        atomicAdd(&cnt[P[e].y & 255], 1);
    __syncthreads();
    int myc = cnt[t];
    s[t] = myc;
    __syncthreads();
    for (int off = 1; off < 256; off <<= 1) {
        int v = (t >= off) ? s[t - off] : 0;
        __syncthreads();
        s[t] += v;
        __syncthreads();
    }
    int excl = s[t] - myc;
    int node = (k << 8) + t;
    if (node < n) {
        rowoff[node] = ebeg + excl;
        dis[node] = rsqrtf((float)(myc + 1));  // +1 self-loop
    }
    cur[t] = ebeg + excl;
    __syncthreads();
    for (int e = ebeg + t; e < eend; e += 256) {
        int2 p = P[e];
        int pos = atomicAdd(&cur[p.y & 255], 1);
        csr_src[pos] = p.x;
    }
}

// ---------- W prep (fused): W -> transposed bf16 hi/lo [col][k] ----------
__global__ __launch_bounds__(256) void wprep_all_kernel(
    const float* __restrict__ W1, const float* __restrict__ Wh, const float* __restrict__ W2,
    unsigned short* __restrict__ W1hi, unsigned short* __restrict__ W1lo,
    unsigned short* __restrict__ Whhi, unsigned short* __restrict__ Whlo,
    unsigned short* __restrict__ W2hi, unsigned short* __restrict__ W2lo) {
    int t = blockIdx.x * 256 + threadIdx.x;
    const float* W;
    unsigned short *Hi, *Lo;
    int nout, lt;
    if (t < 16384)      { W = W1; Hi = W1hi; Lo = W1lo; nout = 128; lt = t; }
    else if (t < 32768) { W = Wh; Hi = Whhi; Lo = Whlo; nout = 128; lt = t - 16384; }
    else if (t < 40960) { W = W2; Hi = W2hi; Lo = W2lo; nout = 64;  lt = t - 32768; }
    else return;
    int col = lt % nout, k = lt / nout;
    float v = W[lt];                       // coalesced (lt == k*nout+col)
    unsigned short hi = f2bf(v);
    unsigned short lo = f2bf(v - bf2f(hi));
    Hi[(size_t)col * 128 + k] = hi;
    Lo[(size_t)col * 128 + k] = lo;
}

// ---------- MFMA GEMM: C[r] = bf16((A[r] @ W) * scale[r]) ----------
// Block = 64 rows x 64 cols, 4 waves. B hi/lo in registers (64 VGPR),
// A hi/lo in LDS (34 KB). Split-bf16 x3: Ah*Bh + Ah*Bl + Al*Bh.
template <int NOUT>
__global__ __launch_bounds__(256) void gemm_mfma_kernel(
    const float* __restrict__ A,
    const unsigned short* __restrict__ Wthi,  // [NOUT][128] bf16
    const unsigned short* __restrict__ Wtlo,
    const float* __restrict__ scale,
    unsigned short* __restrict__ C, int M) {
    constexpr int LDK = 136;  // shorts; 16 B-aligned frags, banks spread
    __shared__ unsigned short sAhi[64 * LDK];
    __shared__ unsigned short sAlo[64 * LDK];

    int tid = threadIdx.x;
    int w = tid >> 6, lane = tid & 63;
    int quad = lane >> 4, m = lane & 15;
    int Rbase = blockIdx.x * 64;
    int Cbase = blockIdx.y * 64;
    int r0 = (w & 1) * 32, c0 = (w >> 1) * 32;

    // B-frags to registers (once per wave): [ks][grp], grp = col 16-group
    short8 bh[4][2], bl[4][2];
#pragma unroll
    for (int ks = 0; ks < 4; ++ks)
#pragma unroll
        for (int g = 0; g < 2; ++g) {
            size_t off = (size_t)(Cbase + c0 + g * 16 + m) * 128 + ks * 32 + quad * 8;
            bh[ks][g] = *(const short8*)(Wthi + off);
            bl[ks][g] = *(const short8*)(Wtlo + off);
        }

    // stage A: 64 rows x 128 fp32 -> hi/lo bf16 in LDS
    for (int i = tid; i < 64 * 32; i += 256) {
        int r = i >> 5, c4 = i & 31;
        int row = Rbase + r;
        float4 v = make_float4(0.f, 0.f, 0.f, 0.f);
        if (row < M) v = ((const float4*)(A + (size_t)row * 128))[c4];
        ushort4 hi, lo;
        hi.x = f2bf(v.x); lo.x = f2bf(v.x - bf2f(hi.x));
        hi.y = f2bf(v.y); lo.y = f2bf(v.y - bf2f(hi.y));
        hi.z = f2bf(v.z); lo.z = f2bf(v.z - bf2f(hi.z));
        hi.w = f2bf(v.w); lo.w = f2bf(v.w - bf2f(hi.w));
        *(ushort4*)(sAhi + r * LDK + c4 * 4) = hi;
        *(ushort4*)(sAlo + r * LDK + c4 * 4) = lo;
    }
    __syncthreads();

    f32x4 z = {0.f, 0.f, 0.f, 0.f};
    f32x4 acc00 = z, acc01 = z, acc10 = z, acc11 = z;

#pragma unroll
    for (int ks = 0; ks < 4; ++ks) {
        int kof = ks * 32 + quad * 8;
        short8 ah0 = *(const short8*)(sAhi + (r0 + m) * LDK + kof);
        short8 ah1 = *(const short8*)(sAhi + (r0 + 16 + m) * LDK + kof);
        short8 al0 = *(const short8*)(sAlo + (r0 + m) * LDK + kof);
        short8 al1 = *(const short8*)(sAlo + (r0 + 16 + m) * LDK + kof);
        // hi*hi + hi*lo + lo*hi (lo*lo dropped, ~2^-18), accs round-robin
        acc00 = __builtin_amdgcn_mfma_f32_16x16x32_bf16(ah0, bh[ks][0], acc00, 0, 0, 0);
        acc01 = __builtin_amdgcn_mfma_f32_16x16x32_bf16(ah0, bh[ks][1], acc01, 0, 0, 0);
        acc10 = __builtin_amdgcn_mfma_f32_16x16x32_bf16(ah1, bh[ks][0], acc10, 0, 0, 0);
        acc11 = __builtin_amdgcn_mfma_f32_16x16x32_bf16(ah1, bh[ks][1], acc11, 0, 0, 0);
        acc00 = __builtin_amdgcn_mfma_f32_16x16x32_bf16(ah0, bl[ks][0], acc00, 0, 0, 0);
        acc01 = __builtin_amdgcn_mfma_f32_16x16x32_bf16(ah0, bl[ks][1], acc01, 0, 0, 0);
        acc10 = __builtin_amdgcn_mfma_f32_16x16x32_bf16(ah1, bl[ks][0], acc10, 0, 0, 0);
        acc11 = __builtin_amdgcn_mfma_f32_16x16x32_bf16(ah1, bl[ks][1], acc11, 0, 0, 0);
        acc00 = __builtin_amdgcn_mfma_f32_16x16x32_bf16(al0, bh[ks][0], acc00, 0, 0, 0);
        acc01 = __builtin_amdgcn_mfma_f32_16x16x32_bf16(al0, bh[ks][1], acc01, 0, 0, 0);
        acc10 = __builtin_amdgcn_mfma_f32_16x16x32_bf16(al1, bh[ks][0], acc10, 0, 0, 0);
        acc11 = __builtin_amdgcn_mfma_f32_16x16x32_bf16(al1, bh[ks][1], acc11, 0, 0, 0);
    }

    // epilogue: C/D layout col = lane&15 (m), row = quad*4 + reg
#pragma unroll
    for (int reg = 0; reg < 4; ++reg) {
        int row0g = Rbase + r0 + quad * 4 + reg;
        if (row0g < M) {
            float sc = scale[row0g];
            C[(size_t)row0g * NOUT + Cbase + c0 + m]      = f2bf(acc00[reg] * sc);
            C[(size_t)row0g * NOUT + Cbase + c0 + 16 + m] = f2bf(acc01[reg] * sc);
        }
        int row1g = row0g + 16;
        if (row1g < M) {
            float sc = scale[row1g];
            C[(size_t)row1g * NOUT + Cbase + c0 + m]      = f2bf(acc10[reg] * sc);
            C[(size_t)row1g * NOUT + Cbase + c0 + 16 + m] = f2bf(acc11[reg] * sc);
        }
    }
}

// ---------- Gather aggregation v2: half-wave row gather ----------
// 2 nodes per wave; 32 lanes x ushort4 (8 B) = one full 256 B row per half.
// Half h handles edges beg+h, beg+h+2, ... ; halves combined via shfl_xor(32).
__global__ __launch_bounds__(256) void aggregate128_kernel(
    const int* __restrict__ rowoff, const int* __restrict__ csr_src,
    const float* __restrict__ dis, const unsigned short* __restrict__ tp,
    const float* __restrict__ bias, float* __restrict__ hout, int n) {
    int wid = (blockIdx.x * 256 + threadIdx.x) >> 6;
    int lane = threadIdx.x & 63;
    int h = lane >> 5, lc = lane & 31;
    int n0 = wid * 2;
    if (n0 >= n) return;
    int n1 = n0 + 1;
    bool has1 = (n1 < n);

    float a0[4] = {0.f, 0.f, 0.f, 0.f};
    float a1[4] = {0.f, 0.f, 0.f, 0.f};

#define ROW128(node) (*((const ushort4*)(tp + (size_t)(node) * 128) + lc))
#define ACC(a, u) { a[0] += bf2f(u.x); a[1] += bf2f(u.y); a[2] += bf2f(u.z); a[3] += bf2f(u.w); }

    // self-loops: half 0 takes node0's, half 1 takes node1's
    if (h == 0) { ushort4 u = ROW128(n0); ACC(a0, u); }
    else if (has1) { ushort4 u = ROW128(n1); ACC(a1, u); }

    int mid = rowoff[n0 + 1];
    int i0 = rowoff[n0] + h;
    int i1 = mid + h;
    int end1 = has1 ? rowoff[n1 + 1] : mid;

    // joint phase, unroll 2: up to 8 rows in flight per wave
    while (i0 + 2 < mid && i1 + 2 < end1) {
        int s0a = csr_src[i0], s0b = csr_src[i0 + 2];
        int s1a = csr_src[i1], s1b = csr_src[i1 + 2];
        ushort4 u0 = ROW128(s0a), u1 = ROW128(s0b);
        ushort4 v0 = ROW128(s1a), v1 = ROW128(s1b);
        ACC(a0, u0); ACC(a0, u1);
        ACC(a1, v0); ACC(a1, v1);
        i0 += 4; i1 += 4;
    }
    for (; i0 < mid; i0 += 2) { ushort4 u = ROW128(csr_src[i0]); ACC(a0, u); }
    for (; i1 < end1; i1 += 2) { ushort4 v = ROW128(csr_src[i1]); ACC(a1, v); }
#undef ROW128

    // combine even/odd halves
#pragma unroll
    for (int j = 0; j < 4; ++j) {
        a0[j] += __shfl_xor(a0[j], 32);
        a1[j] += __shfl_xor(a1[j], 32);
    }

    float4 b = ((const float4*)bias)[lc];
    if (h == 0) {
        float dd = dis[n0];
        float4 r;
        r.x = fmaxf(a0[0] * dd + b.x, 0.f);
        r.y = fmaxf(a0[1] * dd + b.y, 0.f);
        r.z = fmaxf(a0[2] * dd + b.z, 0.f);
        r.w = fmaxf(a0[3] * dd + b.w, 0.f);
        ((float4*)(hout + (size_t)n0 * 128))[lc] = r;
    } else if (has1) {
        float dd = dis[n1];
        float4 r;
        r.x = fmaxf(a1[0] * dd + b.x, 0.f);
        r.y = fmaxf(a1[1] * dd + b.y, 0.f);
        r.z = fmaxf(a1[2] * dd + b.z, 0.f);
        r.w = fmaxf(a1[3] * dd + b.w, 0.f);
        ((float4*)(hout + (size_t)n1 * 128))[lc] = r;
    }
}

// F=64 + fused head. 32 lanes x ushort2 (4 B) = one 128 B row per half.
__global__ __launch_bounds__(256) void aggregate64_head_kernel(
    const int* __restrict__ rowoff, const int* __restrict__ csr_src,
    const float* __restrict__ dis, const unsigned short* __restrict__ tp,
    const float* __restrict__ bias, const float* __restrict__ Wout,
    const float* __restrict__ bout, float* __restrict__ hout,
    float* __restrict__ out, int n) {
    int wid = (blockIdx.x * 256 + threadIdx.x) >> 6;
    int lane = threadIdx.x & 63;
    int h = lane >> 5, lc = lane & 31;
    int n0 = wid * 2;
    if (n0 >= n) return;
    int n1 = n0 + 1;
    bool has1 = (n1 < n);

    float a0[2] = {0.f, 0.f};
    float a1[2] = {0.f, 0.f};

#define ROW64(node) (*((const ushort2*)(tp + (size_t)(node) * 64) + lc))
#define ACC2(a, u) { a[0] += bf2f(u.x); a[1] += bf2f(u.y); }

    if (h == 0) { ushort2 u = ROW64(n0); ACC2(a0, u); }
    else if (has1) { ushort2 u = ROW64(n1); ACC2(a1, u); }

    int mid = rowoff[n0 + 1];
    int i0 = rowoff[n0] + h;
    int i1 = mid + h;
    int end1 = has1 ? rowoff[n1 + 1] : mid;

    while (i0 + 2 < mid && i1 + 2 < end1) {
        int s0a = csr_src[i0], s0b = csr_src[i0 + 2];
        int s1a = csr_src[i1], s1b = csr_src[i1 + 2];
        ushort2 u0 = ROW64(s0a), u1 = ROW64(s0b);
        ushort2 v0 = ROW64(s1a), v1 = ROW64(s1b);
        ACC2(a0, u0); ACC2(a0, u1);
        ACC2(a1, v0); ACC2(a1, v1);
        i0 += 4; i1 += 4;
    }
    for (; i0 < mid; i0 += 2) { ushort2 u = ROW64(csr_src[i0]); ACC2(a0, u); }
    for (; i1 < end1; i1 += 2) { ushort2 v = ROW64(csr_src[i1]); ACC2(a1, v); }
#undef ROW64

#pragma unroll
    for (int j = 0; j < 2; ++j) {
        a0[j] += __shfl_xor(a0[j], 32);
        a1[j] += __shfl_xor(a1[j], 32);
    }

    // epilogue per half: half 0 -> node0, half 1 -> node1
    int node = h ? n1 : n0;
    float* ap = h ? a1 : a0;
    bool valid = (h == 0) || has1;
    float2 hv = make_float2(0.f, 0.f);
    if (valid) {
        float dd = dis[node];
        float2 b = ((const float2*)bias)[lc];
        hv.x = ap[0] * dd + b.x;
        hv.y = ap[1] * dd + b.y;
        ((float2*)(hout + (size_t)node * 64))[lc] = hv;
    }
    float2 wv = ((const float2*)Wout)[lc];
    float p = valid ? (hv.x * wv.x + hv.y * wv.y) : 0.f;
#pragma unroll
    for (int off = 16; off > 0; off >>= 1) p += __shfl_down(p, off);
    if (lc == 0 && valid) out[node] = p + bout[0];
}

extern "C" void kernel_launch(void* const* d_in, const int* in_sizes, int n_in,
                              void* d_out, int out_size, void* d_ws, size_t ws_size,
                              hipStream_t stream) {
    const float* x    = (const float*)d_in[0];
    const int*   ei   = (const int*)d_in[1];  // [2, E] flat: src then dst
    const float* W1   = (const float*)d_in[2];
    const float* b1   = (const float*)d_in[3];
    const float* Wh   = (const float*)d_in[4];
    const float* bh   = (const float*)d_in[5];
    const float* W2   = (const float*)d_in[6];
    const float* b2   = (const float*)d_in[7];
    const float* Wout = (const float*)d_in[8];
    const float* bout = (const float*)d_in[9];

    const int N = N_NODES;
    const int E = N_EDGES;
    const int* srcv = ei;
    const int* dstv = ei + E;

    float* out  = (float*)d_out;            // [N]
    float* hout = (float*)d_out + N;        // [N x 64]

    char* ws = (char*)d_ws;
    int*   H       = (int*)ws;                          ws += sizeof(int) * NBUCK * GB;
    int*   bsum    = (int*)ws;                          ws += sizeof(int) * NBUCK;
    int*   bstart  = (int*)ws;                          ws += sizeof(int) * (NBUCK + 1);
    int*   rowoff  = (int*)ws;                          ws += sizeof(int) * (N + 1);
    int2*  P       = (int2*)ws;                         ws += sizeof(int2) * E;
    int*   csr_src = (int*)ws;                          ws += sizeof(int) * E;
    float* dis     = (float*)ws;                        ws += sizeof(float) * N;
    unsigned short* W1thi = (unsigned short*)ws;        ws += sizeof(unsigned short) * 128 * 128;
    unsigned short* W1tlo = (unsigned short*)ws;        ws += sizeof(unsigned short) * 128 * 128;
    unsigned short* Whthi = (unsigned short*)ws;        ws += sizeof(unsigned short) * 128 * 128;
    unsigned short* Whtlo = (unsigned short*)ws;        ws += sizeof(unsigned short) * 128 * 128;
    unsigned short* W2thi = (unsigned short*)ws;        ws += sizeof(unsigned short) * 64 * 128;
    unsigned short* W2tlo = (unsigned short*)ws;        ws += sizeof(unsigned short) * 64 * 128;
    unsigned short* bufT  = (unsigned short*)ws;        ws += sizeof(unsigned short) * (size_t)N * 128;
    float* bufH    = (float*)ws;                        // N*128 fp32

    // --- W prep (fused, bf16 hi/lo transposed) ---
    wprep_all_kernel<<<160, 256, 0, stream>>>(W1, Wh, W2, W1thi, W1tlo, Whthi, Whtlo, W2thi, W2tlo);

    // --- CSR build (two-level counting sort, hierarchical scan) ---
    hist_kernel<<<GB, 256, 0, stream>>>(dstv, H, E);
    scan1_kernel<<<NBUCK, 256, 0, stream>>>(H, bsum);
    scan2_kernel<<<1, 256, 0, stream>>>(bsum, bstart, rowoff + N);
    partition_kernel<<<GB, 256, 0, stream>>>(srcv, dstv, H, bstart, P, E);
    bucket_csr_kernel<<<NBUCK, 256, 0, stream>>>(P, bstart, rowoff, dis, csr_src, N);

    const int aggBlocks = ((N + 1) / 2 * 64 + 255) / 256;  // 2 nodes per wave
    const int gemmRows = (N + 63) / 64;                    // 782

    // --- layer 1: h1 = relu(agg(x@W1) + b1) ---
    gemm_mfma_kernel<128><<<dim3(gemmRows, 2), 256, 0, stream>>>(x, W1thi, W1tlo, dis, bufT, N);
    aggregate128_kernel<<<aggBlocks, 256, 0, stream>>>(rowoff, csr_src, dis, bufT, b1, bufH, N);

    // --- layer 2: h2 = relu(agg(h1@Wh) + bh) ---
    gemm_mfma_kernel<128><<<dim3(gemmRows, 2), 256, 0, stream>>>(bufH, Whthi, Whtlo, dis, bufT, N);
    aggregate128_kernel<<<aggBlocks, 256, 0, stream>>>(rowoff, csr_src, dis, bufT, bh, bufH, N);

    // --- layer 3 + head: h3 = agg(h2@W2) + b2 ; out = h3@Wout + bout ---
    gemm_mfma_kernel<64><<<dim3(gemmRows, 1), 256, 0, stream>>>(bufH, W2thi, W2tlo, dis, bufT, N);
    aggregate64_head_kernel<<<aggBlocks, 256, 0, stream>>>(
        rowoff, csr_src, dis, bufT, b2, Wout, bout, hout, out, N);
}